// Round 7
// baseline (531.162 us; speedup 1.0000x reference)
//
#include <hip/hip_runtime.h>
#include <hip/hip_bf16.h>

// Problem dims (fixed)
#define Nn   512
#define NN   262144        // N*N positions
#define EDG  16384

typedef unsigned short u16;
typedef unsigned int u32;
typedef short v8s __attribute__((ext_vector_type(8)));   // 8 bf16 lanes (4 VGPR)
typedef float v4f __attribute__((ext_vector_type(4)));
typedef u16 u16x8 __attribute__((ext_vector_type(8)));

__device__ __forceinline__ float b2f(u16 u) {
    union { unsigned int i; float f; } v; v.i = ((unsigned int)u) << 16; return v.f;
}
__device__ __forceinline__ u16 f2b(float f) {
    union { float f; unsigned int i; } v; v.f = f;
    unsigned int r = (v.i + 0x7FFFu + ((v.i >> 16) & 1u)) >> 16;
    return (u16)r;
}
// affine on a packed pair of bf16 (2 positions of one channel)
__device__ __forceinline__ u32 aff2(u32 x, float s, float h) {
    float lo = b2f((u16)(x & 0xFFFFu)) * s + h;
    float hi = b2f((u16)(x >> 16)) * s + h;
    return (u32)f2b(lo) | ((u32)f2b(hi) << 16);
}

// ---------------------------------------------------------------------------
__global__ void sentinel_kernel(float* __restrict__ out, float val) {
    if (threadIdx.x < 10) out[threadIdx.x] = val;
}

// ---------------------------------------------------------------------------
// K0: convert the 6 conv weight tensors (fp32) into one bf16 arena.
__global__ void cvt_weights(const float* __restrict__ s0, const float* __restrict__ s1,
                            const float* __restrict__ s2, const float* __restrict__ s3,
                            const float* __restrict__ s4, const float* __restrict__ s5,
                            u16* __restrict__ dst) {
    int t = blockIdx.x * 256 + threadIdx.x;
    if (t >= 43008) return;
    float v;
    if      (t < 2048)  v = s0[t];
    else if (t < 4096)  v = s1[t - 2048];
    else if (t < 10240) v = s2[t - 4096];
    else if (t < 18432) v = s3[t - 10240];
    else if (t < 26624) v = s4[t - 18432];
    else                v = s5[t - 26624];
    dst[t] = f2b(v);
}

// ---------------------------------------------------------------------------
// K1: scatter edges into A (fp32, pos-major [p][32]); x is fp32 [512][16]
__global__ void scatter_edges(const float* __restrict__ x, const int* __restrict__ ei,
                              float* __restrict__ A) {
    int t = blockIdx.x * 256 + threadIdx.x;
    if (t >= EDG * 32) return;
    int e = t >> 5, c = t & 31;
    int s = ei[e], d = ei[EDG + e];
    float v = (c < 16) ? x[s * 16 + c] : x[d * 16 + (c - 16)];
    atomicAdd(A + ((size_t)s * Nn + d) * 32 + c, v);
}

// ---------------------------------------------------------------------------
// K2: A fp32 pos-major [p][32] -> u0 CHANNEL-MAJOR bf16 [32][NN]; totals into tt0[64..]
__global__ __launch_bounds__(256) void finalize_u0(const float* __restrict__ A,
                                                   u16* __restrict__ u0,
                                                   float* __restrict__ total) {
    __shared__ u16 L[32 * 258];
    __shared__ float red[4][32];
    int t = threadIdx.x;
    int p0 = blockIdx.x * 256;
    const float* Ar = A + (size_t)(p0 + t) * 32;
    float v[32];
#pragma unroll
    for (int c = 0; c < 32; ++c) v[c] = Ar[c];
#pragma unroll
    for (int c = 0; c < 32; ++c) L[c * 258 + t] = f2b(v[c]);
    int wv = t >> 6;
#pragma unroll
    for (int c = 0; c < 32; ++c) {
        float r = v[c];
        for (int off = 32; off > 0; off >>= 1) r += __shfl_down(r, off);
        if ((t & 63) == 0) red[wv][c] = r;
    }
    __syncthreads();
    if (t < 32) atomicAdd(total + t, red[0][t] + red[1][t] + red[2][t] + red[3][t]);
    int off = (t & 31) * 8, rb = t >> 5;
#pragma unroll
    for (int pass = 0; pass < 4; ++pass) {
        int c = pass * 8 + rb;
        u16x8 w = *(const u16x8*)(L + c * 258 + off);
        *(u16x8*)(u0 + (size_t)c * NN + p0 + off) = w;
    }
}

// ---------------------------------------------------------------------------
// K3: trace of channel-major activation; grid = C blocks.
__global__ void trace_raw_cm(const u16* __restrict__ ucm, float* __restrict__ trraw) {
    int c = blockIdx.x, t = threadIdx.x;
    const u16* base = ucm + (size_t)c * NN;
    float s = b2f(base[(size_t)(2 * t) * 513]) + b2f(base[(size_t)(2 * t + 1) * 513]);
    for (int off = 32; off > 0; off >>= 1) s += __shfl_down(s, off);
    __shared__ float r[4];
    if ((t & 63) == 0) r[t >> 6] = s;
    __syncthreads();
    if (t == 0) trraw[c] = r[0] + r[1] + r[2] + r[3];
}

// ---------------------------------------------------------------------------
// K5 v2: streaming conv1+conv2 (verified r4). Grid 512 x 512 thr, 4 tiles of
// 128 positions per block; weights in registers; pack-transpose LDS staging.
// Epilogue waves cover full 128B lines (wn*64 + 4x nt*16) -> no write amp.
template<int CIN>
__global__ __launch_bounds__(512, 4) void conv12_s(
    const u16* __restrict__ src,
    const float* __restrict__ sc, const float* __restrict__ sh,
    const u16* __restrict__ w1, const float* __restrict__ b1,
    const u16* __restrict__ w2, const float* __restrict__ b2,
    u16* __restrict__ dst1, u16* __restrict__ dst2)
{
    constexpr int G    = CIN / 8;            // 16B granules per position row
    constexpr int LOGG = (CIN == 64) ? 3 : 2;
    constexpr int ROWB = CIN * 2;            // bytes per position row
    constexpr int KC   = CIN / 32;
    constexpr int PASSES = CIN / 32;         // stage passes (512 u32-units each)

    __shared__ char LB[2][128 * ROWB];

    const int t = threadIdx.x;
    const int lane = t & 63, w = t >> 6;
    const int l15 = lane & 15, quad = lane >> 4;
    const int wr = w >> 1;                   // 4 M-groups of 32 rows
    const int wn = w & 1;                    // 2 N-groups of 64 positions
    const size_t Pblk = (size_t)blockIdx.x * 512;

    // ---- stage-role mapping (flat threads)
    const int cpair = (CIN == 64) ? (t >> 4) : (t >> 5);   // channel pair index
    const int pg    = (CIN == 64) ? (t & 15) : (t & 31);   // 4-position group
    const int g0    = cpair >> 2;
    const int word  = cpair & 3;
    const u16* srcA = src + (size_t)(2 * cpair) * NN;
    float s0 = 1.f, h0 = 0.f, s1 = 1.f, h1 = 0.f;
    const bool aff = (sc != nullptr);
    if (aff) { s0 = sc[2 * cpair]; h0 = sh[2 * cpair]; s1 = sc[2 * cpair + 1]; h1 = sh[2 * cpair + 1]; }

    // ---- weights in registers: stacked rows [w1; w2], this wave owns 32 rows
    v8s af[2][KC];
#pragma unroll
    for (int mt = 0; mt < 2; ++mt) {
        const int row = wr * 32 + mt * 16 + l15;
        const u16* Wm = (row < 64) ? (w1 + row * CIN) : (w2 + (row - 64) * CIN);
#pragma unroll
        for (int kc = 0; kc < KC; ++kc)
            af[mt][kc] = *(const v8s*)(Wm + kc * 32 + quad * 8);
    }
    float bias[2][4];
#pragma unroll
    for (int mt = 0; mt < 2; ++mt)
#pragma unroll
        for (int r = 0; r < 4; ++r) {
            const int row = wr * 32 + mt * 16 + quad * 4 + r;
            bias[mt][r] = (row < 64) ? b1[row] : b2[row - 64];
        }

    v4f acc[2][4];
#pragma unroll
    for (int mt = 0; mt < 2; ++mt)
#pragma unroll
        for (int nt = 0; nt < 4; ++nt) acc[mt][nt] = (v4f){0.f, 0.f, 0.f, 0.f};

    uint2 ea[PASSES], eb[PASSES];

#define C12_LOAD(T)                                                           \
    _Pragma("unroll")                                                         \
    for (int pp = 0; pp < PASSES; ++pp) {                                     \
        const int p0_ = (pg + ((CIN == 64) ? 16 : 0) * pp) * 4;               \
        const u16* sp_ = srcA + Pblk + (size_t)(T) * 128 + p0_;               \
        ea[pp] = *(const uint2*)sp_;                                          \
        eb[pp] = *(const uint2*)(sp_ + NN);                                   \
    }

#define C12_WRITE(BUF)                                                        \
    {                                                                         \
        char* Lb_ = LB[BUF];                                                  \
        _Pragma("unroll")                                                     \
        for (int pp = 0; pp < PASSES; ++pp) {                                 \
            const int p0_ = (pg + ((CIN == 64) ? 16 : 0) * pp) * 4;           \
            u32 A0 = ea[pp].x, A1 = ea[pp].y, B0 = eb[pp].x, B1 = eb[pp].y;   \
            if (aff) {                                                        \
                A0 = aff2(A0, s0, h0); A1 = aff2(A1, s0, h0);                 \
                B0 = aff2(B0, s1, h1); B1 = aff2(B1, s1, h1);                 \
            }                                                                 \
            u32 pk0 = (A0 & 0xFFFFu) | (B0 << 16);                            \
            u32 pk1 = (A0 >> 16) | (B0 & 0xFFFF0000u);                        \
            u32 pk2 = (A1 & 0xFFFFu) | (B1 << 16);                            \
            u32 pk3 = (A1 >> 16) | (B1 & 0xFFFF0000u);                        \
            _Pragma("unroll")                                                 \
            for (int w4 = 0; w4 < 4; ++w4) {                                  \
                const int p_ = p0_ + w4;                                      \
                const int g_ = g0 ^ (p_ & (G - 1)) ^ ((p_ >> LOGG) & (G - 1));\
                u32 v_ = (w4 == 0) ? pk0 : (w4 == 1) ? pk1 : (w4 == 2) ? pk2 : pk3; \
                *(u32*)(Lb_ + p_ * ROWB + g_ * 16 + word * 4) = v_;           \
            }                                                                 \
        }                                                                     \
    }

#define C12_COMPUTE(BUF)                                                      \
    _Pragma("unroll")                                                         \
    for (int kc = 0; kc < KC; ++kc) {                                         \
        v8s bf_[4];                                                           \
        const char* Lb_ = LB[BUF];                                            \
        _Pragma("unroll")                                                     \
        for (int nt = 0; nt < 4; ++nt) {                                      \
            const int p_ = wn * 64 + nt * 16 + l15;                           \
            const int lg_ = kc * 4 + quad;                                    \
            const int g_ = lg_ ^ (p_ & (G - 1)) ^ ((p_ >> LOGG) & (G - 1));   \
            bf_[nt] = *(const v8s*)(Lb_ + p_ * ROWB + g_ * 16);               \
        }                                                                     \
        _Pragma("unroll")                                                     \
        for (int mt = 0; mt < 2; ++mt)                                        \
            _Pragma("unroll")                                                 \
            for (int nt = 0; nt < 4; ++nt)                                    \
                acc[mt][nt] = __builtin_amdgcn_mfma_f32_16x16x32_bf16(        \
                    af[mt][kc], bf_[nt], acc[mt][nt], 0, 0, 0);               \
    }

    // ---- prologue
    C12_LOAD(0)
    C12_WRITE(0)
    __syncthreads();

#pragma unroll
    for (int T = 0; T < 4; ++T) {
        const int cur = T & 1;
        if (T < 3) C12_LOAD(T + 1)
        C12_COMPUTE(cur)
        // epilogue: direct channel-major stores
#pragma unroll
        for (int mt = 0; mt < 2; ++mt)
#pragma unroll
            for (int r = 0; r < 4; ++r) {
                const int row = wr * 32 + mt * 16 + quad * 4 + r;
                u16* dp = ((row < 64) ? (dst1 + (size_t)row * NN)
                                      : (dst2 + (size_t)(row - 64) * NN))
                          + Pblk + (size_t)T * 128 + wn * 64 + l15;
#pragma unroll
                for (int nt = 0; nt < 4; ++nt) {
                    u16 v = f2b(acc[mt][nt][r] + bias[mt][r]);
                    __builtin_nontemporal_store(v, dp + nt * 16);
                }
            }
        // acc reset for next tile
#pragma unroll
        for (int mt = 0; mt < 2; ++mt)
#pragma unroll
            for (int nt = 0; nt < 4; ++nt) acc[mt][nt] = (v4f){0.f,0.f,0.f,0.f};
        if (T < 3) {
            C12_WRITE(cur ^ 1)
            __syncthreads();
        }
    }
#undef C12_LOAD
#undef C12_WRITE
#undef C12_COMPUTE
}

// ---------------------------------------------------------------------------
// K6 v2: streaming m4 conv for K=128 (layers 1-2), write-amp fixed.
// 512 blocks x 512 thr, 4 tiles of 128 positions. SINGLE 32KB input buffer
// (regs carry tile T+1) -> 3 blocks/CU. Wave roles: wq=w>>1 owns 16 output
// rows (quad*4+r), wn=w&1 owns a 64-position half, nt<4 -> each wave's 4 nt
// stores cover a FULL 128B line per channel (bmm/conv12 proven shape).
// BN sum/sumsq in registers; trace element picked predicated.
__global__ __launch_bounds__(512, 6) void conv4_s(
    const u16* __restrict__ mult, const u16* __restrict__ u,
    const float* __restrict__ sc, const float* __restrict__ sh,
    const u16* __restrict__ w, const float* __restrict__ bias,
    u16* __restrict__ dst,
    float* __restrict__ psum, float* __restrict__ psq, float* __restrict__ ptr)
{
    constexpr int ROWB = 256;                // 128 ch * 2B
    __shared__ char IN[128 * ROWB];          // 32 KB single buffer
    __shared__ float R1[64][2], R2[64][2];

    const int t = threadIdx.x;
    const int lane = t & 63, w8 = t >> 6;
    const int l15 = lane & 15, quad = lane >> 4;
    const int wq = w8 >> 1;                  // 4 row-groups of 16
    const int wn = w8 & 1;                   // 2 pos-halves of 64
    const int brow = blockIdx.x;             // block owns matrix row brow
    const size_t Pblk = (size_t)brow * 512;

    // stage mapping: 64 channel-pairs x 8 pos-groups, 4 position passes
    const int pair = t >> 3;
    const int pg = t & 7;
    const int g0 = pair >> 2;
    const int word = pair & 3;
    const bool isU = pair >= 32;
    const u16* srcA = isU ? (u + (size_t)(2 * pair - 64) * NN)
                          : (mult + (size_t)(2 * pair) * NN);
    float s0 = 1.f, h0 = 0.f, s1 = 1.f, h1 = 0.f;
    const bool doaff = isU && (sc != nullptr);
    if (doaff) { s0 = sc[2 * pair - 64]; h0 = sh[2 * pair - 64];
                 s1 = sc[2 * pair - 63]; h1 = sh[2 * pair - 63]; }

    // weights + bias in registers: this wave-group owns rows wq*16..wq*16+15
    v8s af[4];
#pragma unroll
    for (int kc = 0; kc < 4; ++kc)
        af[kc] = *(const v8s*)(w + (wq * 16 + l15) * 128 + kc * 32 + quad * 8);
    float bv_[4];
#pragma unroll
    for (int r = 0; r < 4; ++r)
        bv_[r] = bias[wq * 16 + quad * 4 + r];

    v4f acc[4];
    float bnS[4], bnQ[4];
#pragma unroll
    for (int nt = 0; nt < 4; ++nt) acc[nt] = (v4f){0.f, 0.f, 0.f, 0.f};
#pragma unroll
    for (int r = 0; r < 4; ++r) { bnS[r] = 0.f; bnQ[r] = 0.f; }

    uint2 ea[4], eb[4];

#define C4_LOAD(T)                                                            \
    _Pragma("unroll")                                                         \
    for (int pp = 0; pp < 4; ++pp) {                                          \
        const int p0_ = (pg + 8 * pp) * 4;                                    \
        const u16* sp_ = srcA + Pblk + (size_t)(T) * 128 + p0_;               \
        ea[pp] = *(const uint2*)sp_;                                          \
        eb[pp] = *(const uint2*)(sp_ + NN);                                   \
    }

#define C4_WRITE()                                                            \
    {                                                                         \
        _Pragma("unroll")                                                     \
        for (int pp = 0; pp < 4; ++pp) {                                      \
            const int p0_ = (pg + 8 * pp) * 4;                                \
            u32 A0 = ea[pp].x, A1 = ea[pp].y, B0 = eb[pp].x, B1 = eb[pp].y;   \
            if (doaff) {                                                      \
                A0 = aff2(A0, s0, h0); A1 = aff2(A1, s0, h0);                 \
                B0 = aff2(B0, s1, h1); B1 = aff2(B1, s1, h1);                 \
            }                                                                 \
            u32 pk0 = (A0 & 0xFFFFu) | (B0 << 16);                            \
            u32 pk1 = (A0 >> 16) | (B0 & 0xFFFF0000u);                        \
            u32 pk2 = (A1 & 0xFFFFu) | (B1 << 16);                            \
            u32 pk3 = (A1 >> 16) | (B1 & 0xFFFF0000u);                        \
            _Pragma("unroll")                                                 \
            for (int w4 = 0; w4 < 4; ++w4) {                                  \
                const int p_ = p0_ + w4;                                      \
                const int g_ = g0 ^ (p_ & 15) ^ ((p_ >> 4) & 15);             \
                u32 v_ = (w4 == 0) ? pk0 : (w4 == 1) ? pk1 : (w4 == 2) ? pk2 : pk3; \
                *(u32*)(IN + p_ * ROWB + g_ * 16 + word * 4) = v_;            \
            }                                                                 \
        }                                                                     \
    }

#define C4_COMPUTE()                                                          \
    _Pragma("unroll")                                                         \
    for (int kc = 0; kc < 4; ++kc) {                                          \
        v8s bf_[4];                                                           \
        _Pragma("unroll")                                                     \
        for (int nt = 0; nt < 4; ++nt) {                                      \
            const int p_ = wn * 64 + nt * 16 + l15;                           \
            const int lg_ = kc * 4 + quad;                                    \
            const int g_ = lg_ ^ (p_ & 15) ^ ((p_ >> 4) & 15);                \
            bf_[nt] = *(const v8s*)(IN + p_ * ROWB + g_ * 16);                \
        }                                                                     \
        _Pragma("unroll")                                                     \
        for (int nt = 0; nt < 4; ++nt)                                        \
            acc[nt] = __builtin_amdgcn_mfma_f32_16x16x32_bf16(                \
                af[kc], bf_[nt], acc[nt], 0, 0, 0);                           \
    }

    // ---- prologue
    C4_LOAD(0)
    C4_WRITE()
    __syncthreads();

#pragma unroll
    for (int T = 0; T < 4; ++T) {
        if (T < 3) C4_LOAD(T + 1)
        C4_COMPUTE()
        __syncthreads();                     // all done reading IN
        if (T < 3) C4_WRITE()                // regs -> IN (next tile)
        // epilogue: full-line channel-major stores + BN accum + trace pick
#pragma unroll
        for (int r = 0; r < 4; ++r) {
            const int c = wq * 16 + quad * 4 + r;
            u16* dp = dst + (size_t)c * NN + Pblk + (size_t)T * 128 + wn * 64 + l15;
#pragma unroll
            for (int nt = 0; nt < 4; ++nt) {
                const int pos = T * 128 + wn * 64 + nt * 16 + l15;
                float fv = acc[nt][r] + bv_[r];
                u16 b16 = f2b(fv);
                float rv = b2f(b16);
                bnS[r] += rv;
                bnQ[r] += rv * rv;
                __builtin_nontemporal_store(b16, dp + nt * 16);
                if (pos == brow) ptr[c * 512 + brow] = rv;
            }
        }
#pragma unroll
        for (int nt = 0; nt < 4; ++nt) acc[nt] = (v4f){0.f, 0.f, 0.f, 0.f};
        if (T < 3) __syncthreads();          // IN ready for next compute
    }

    // ---- BN partial reduction: 16-lane butterfly, then across the 2 wn waves
#pragma unroll
    for (int r = 0; r < 4; ++r) {
        float s = bnS[r], q = bnQ[r];
#pragma unroll
        for (int m = 1; m < 16; m <<= 1) {
            s += __shfl_xor(s, m);
            q += __shfl_xor(q, m);
        }
        if (l15 == 0) {
            const int c = wq * 16 + quad * 4 + r;
            R1[c][wn] = s; R2[c][wn] = q;
        }
    }
    __syncthreads();
    if (t < 64) {
        psum[t * 2048 + brow] = R1[t][0] + R1[t][1];
        psq[t * 2048 + brow]  = R2[t][0] + R2[t][1];
    }
#undef C4_LOAD
#undef C4_WRITE
#undef C4_COMPUTE
}

// ---------------------------------------------------------------------------
// K6: m4 conv (r9, proven) — kept for layer 0 (K=96).
template<int NCH>
__global__ __launch_bounds__(256) void conv4_t(
    const u16* __restrict__ mult, const u16* __restrict__ u,
    const float* __restrict__ sc, const float* __restrict__ sh,
    const u16* __restrict__ w, const float* __restrict__ bias,
    u16* __restrict__ dst,
    float* __restrict__ psum, float* __restrict__ psq, float* __restrict__ ptr)
{
    __shared__ u16 LS[8320];
    __shared__ float R1[64][4], R2[64][4];
    const int K = NCH * 32;
    const int t = threadIdx.x;
    const int P0 = blockIdx.x * 128;
    const int lane = t & 63, wave = t >> 6;
    const int l15 = lane & 15, quad = lane >> 4;
    const int pw = wave * 32;
    const int sr = t >> 4;
    const int so = (t & 15) * 8;

    u16x8 pf[NCH][2];
#pragma unroll
    for (int kc = 0; kc < NCH; ++kc)
#pragma unroll
        for (int ps = 0; ps < 2; ++ps) {
            int cg = kc * 32 + ps * 16 + sr;
            const u16* gp = (cg < 64) ? (mult + (size_t)cg * NN + P0 + so)
                                      : (u + (size_t)(cg - 64) * NN + P0 + so);
            pf[kc][ps] = *(const u16x8*)gp;
        }

    v4f acc[4][2];
#pragma unroll
    for (int mt = 0; mt < 4; ++mt)
#pragma unroll
        for (int nt = 0; nt < 2; ++nt) acc[mt][nt] = (v4f){0.f, 0.f, 0.f, 0.f};

#pragma unroll
    for (int ps = 0; ps < 2; ++ps)
        *(u16x8*)(LS + (ps * 16 + sr) * 130 + so) = pf[0][ps];
    __syncthreads();
#pragma unroll
    for (int kc = 0; kc < NCH; ++kc) {
        if (kc + 1 < NCH) {
            u16* Ln = LS + ((kc + 1) & 1) * 4160;
#pragma unroll
            for (int ps = 0; ps < 2; ++ps) {
                int c = ps * 16 + sr;
                int cg = (kc + 1) * 32 + c;
                u16x8 v = pf[kc + 1][ps];
                if (cg >= 64 && sc) {
                    float s = sc[cg - 64], f = sh[cg - 64];
#pragma unroll
                    for (int j = 0; j < 8; ++j) v[j] = f2b(b2f(v[j]) * s + f);
                }
                *(u16x8*)(Ln + c * 130 + so) = v;
            }
        }
        v8s af[4];
#pragma unroll
        for (int mt = 0; mt < 4; ++mt)
            af[mt] = *(const v8s*)(w + (mt * 16 + l15) * K + kc * 32 + quad * 8);
        const u16* Lb = LS + (kc & 1) * 4160;
#pragma unroll
        for (int nt = 0; nt < 2; ++nt) {
            const int p = pw + nt * 16 + l15;
            v8s b;
#pragma unroll
            for (int j = 0; j < 8; ++j) b[j] = (short)Lb[(quad * 8 + j) * 130 + p];
#pragma unroll
            for (int mt = 0; mt < 4; ++mt)
                acc[mt][nt] = __builtin_amdgcn_mfma_f32_16x16x32_bf16(af[mt], b, acc[mt][nt], 0, 0, 0);
        }
        if (kc + 1 < NCH) __syncthreads();
    }
    __syncthreads();
#pragma unroll
    for (int mt = 0; mt < 4; ++mt)
#pragma unroll
        for (int r = 0; r < 4; ++r) {
            const int h = mt * 16 + quad * 4 + r;
            const float bv = bias[h];
#pragma unroll
            for (int nt = 0; nt < 2; ++nt)
                LS[h * 130 + pw + nt * 16 + l15] = f2b(acc[mt][nt][r] + bv);
        }
    __syncthreads();
    {
        int c = t >> 2, q = t & 3;
        const u16* row = LS + c * 130 + q * 32;
        float s = 0.f, s2 = 0.f;
#pragma unroll
        for (int i = 0; i < 32; ++i) { float v = b2f(row[i]); s += v; s2 += v * v; }
        R1[c][q] = s; R2[c][q] = s2;
    }
    __syncthreads();
    {
        int i = P0 >> 9, j0 = P0 & 511;
        int blk = blockIdx.x;
        if (t < 64) {
            psum[t * 2048 + blk] = R1[t][0] + R1[t][1] + R1[t][2] + R1[t][3];
            psq[t * 2048 + blk]  = R2[t][0] + R2[t][1] + R2[t][2] + R2[t][3];
            if (j0 <= i && i < j0 + 128) ptr[t * 512 + i] = b2f(LS[t * 130 + (i - j0)]);
        }
    }
#pragma unroll
    for (int ps = 0; ps < 4; ++ps) {
        int h = ps * 16 + sr;
        u16x8 v = *(const u16x8*)(LS + h * 130 + so);
        __builtin_nontemporal_store(v, (u16x8*)(dst + (size_t)h * NN + P0 + so));
    }
}

// ---------------------------------------------------------------------------
// K7 v5: batched per-channel GEMM, 256x256 tile, 8 waves (verified r1).
__global__ __launch_bounds__(512, 2) void bmm_mfma256(const u16* __restrict__ Aall,
                                                      const u16* __restrict__ Ball,
                                                      u16* __restrict__ Call) {
    __shared__ u16 LA[2][16384];   // [buf][256 rows][64 k]  (granule-swizzled)
    __shared__ u16 LB[2][16384];   // [buf][256 cols j][64 k] (transposed, swizzled)

    const int bid = blockIdx.x;
    const int h  = ((bid >> 5) << 3) | (bid & 7);   // channel; XCD = h&7
    const int qq = (bid >> 3) & 3;
    const int ty = qq >> 1, tx = qq & 1;
    const int t = threadIdx.x;
    const int l = t & 63, w = t >> 6;
    const int l15 = l & 15, quad = l >> 4;
    const int wr = w >> 2, wc = w & 3;              // 2x4 wave grid

    const u16* Ap = Aall + (size_t)h * NN + (size_t)ty * 256 * 512;
    const u16* Bp = Ball + (size_t)h * NN + tx * 256;
    u16* Cp = Call + (size_t)h * NN;

    const int a_m = l >> 3;
    const int a_kg = (l & 7) ^ a_m;
    const u16* ApL = Ap + (size_t)a_m * 512 + a_kg * 8;   // + cc*4096 + k0

    v4f acc[8][4];
#pragma unroll
    for (int mt = 0; mt < 8; ++mt)
#pragma unroll
        for (int nt = 0; nt < 4; ++nt) acc[mt][nt] = (v4f){0.f, 0.f, 0.f, 0.f};

    uint2 eB[4], oB[4];

#define BMM_BLOAD(K0)                                                         \
    _Pragma("unroll")                                                         \
    for (int L = 0; L < 4; ++L) {                                             \
        const int p = w + 8 * L;                                              \
        const u16* s_ = Bp + (size_t)((K0) + 2 * p) * 512 + l * 4;            \
        eB[L] = *(const uint2*)s_;                                            \
        oB[L] = *(const uint2*)(s_ + 512);                                    \
    }

#define BMM_ALOAD(BUF, K0)                                                    \
    _Pragma("unroll")                                                         \
    for (int c = 0; c < 4; ++c) {                                             \
        const int cc = w * 4 + c;                                             \
        __builtin_amdgcn_global_load_lds(                                     \
            (const void*)(ApL + (size_t)cc * 4096 + (K0)),                    \
            (void*)&LA[BUF][cc * 512], 16, 0, 0);                             \
    }

#define BMM_BWRITE(BUF)                                                       \
    {                                                                         \
        char* base_ = (char*)&LB[BUF][0];                                     \
        _Pragma("unroll")                                                     \
        for (int L = 0; L < 4; ++L) {                                         \
            const int p = w + 8 * L;                                          \
            const int gk = p >> 2, wd = p & 3;                                \
            u32 e0 = eB[L].x, e1 = eB[L].y, o0 = oB[L].x, o1 = oB[L].y;       \
            u32 pk0 = (e0 & 0xFFFFu) | (o0 << 16);                            \
            u32 pk1 = (e0 >> 16) | (o0 & 0xFFFF0000u);                        \
            u32 pk2 = (e1 & 0xFFFFu) | (o1 << 16);                            \
            u32 pk3 = (e1 >> 16) | (o1 & 0xFFFF0000u);                        \
            _Pragma("unroll")                                                 \
            for (int q = 0; q < 4; ++q) {                                     \
                const int j = l * 4 + q;                                      \
                const int g = gk ^ (j & 7) ^ ((j >> 3) & 7);                  \
                u32 v_ = (q == 0) ? pk0 : (q == 1) ? pk1 : (q == 2) ? pk2 : pk3; \
                *(u32*)(base_ + j * 128 + (g << 4) + wd * 4) = v_;            \
            }                                                                 \
        }                                                                     \
    }

#define BMM_COMPUTE(BUF)                                                      \
    _Pragma("unroll")                                                         \
    for (int kk = 0; kk < 2; ++kk) {                                          \
        v8s af_[8], bf_[4];                                                   \
        const char* baseA_ = (const char*)&LA[BUF][0];                        \
        const char* baseB_ = (const char*)&LB[BUF][0];                        \
        _Pragma("unroll")                                                     \
        for (int mt = 0; mt < 8; ++mt) {                                      \
            const int m = wr * 128 + mt * 16 + l15;                           \
            const int g = (kk * 4 + quad) ^ (m & 7);                          \
            af_[mt] = *(const v8s*)(baseA_ + m * 128 + (g << 4));             \
        }                                                                     \
        _Pragma("unroll")                                                     \
        for (int nt = 0; nt < 4; ++nt) {                                      \
            const int j = wc * 64 + nt * 16 + l15;                            \
            const int g = (kk * 4 + quad) ^ (j & 7) ^ ((j >> 3) & 7);         \
            bf_[nt] = *(const v8s*)(baseB_ + j * 128 + (g << 4));             \
        }                                                                     \
        _Pragma("unroll")                                                     \
        for (int mt = 0; mt < 8; ++mt)                                        \
            _Pragma("unroll")                                                 \
            for (int nt = 0; nt < 4; ++nt)                                    \
                acc[mt][nt] = __builtin_amdgcn_mfma_f32_16x16x32_bf16(        \
                    af_[mt], bf_[nt], acc[mt][nt], 0, 0, 0);                  \
    }

    BMM_BLOAD(0)
    BMM_ALOAD(0, 0)
    BMM_BWRITE(0)
    __syncthreads();

#pragma unroll 2
    for (int ts = 0; ts < 8; ++ts) {
        const int cur = ts & 1;
        if (ts < 7) {
            BMM_BLOAD((ts + 1) * 64)
            BMM_ALOAD(cur ^ 1, (ts + 1) * 64)
        }
        BMM_COMPUTE(cur)
        if (ts < 7) {
            BMM_BWRITE(cur ^ 1)
            __syncthreads();
        }
    }

#pragma unroll
    for (int mt = 0; mt < 8; ++mt)
#pragma unroll
        for (int r = 0; r < 4; ++r) {
            const int i = ty * 256 + wr * 128 + mt * 16 + quad * 4 + r;
#pragma unroll
            for (int nt = 0; nt < 4; ++nt) {
                const int j = tx * 256 + wc * 64 + nt * 16 + l15;
                Cp[(size_t)i * 512 + j] = f2b(acc[mt][nt][r]);
            }
        }
#undef BMM_BLOAD
#undef BMM_ALOAD
#undef BMM_BWRITE
#undef BMM_COMPUTE
}

// ---------------------------------------------------------------------------
// K11: reduce per-block partials; BN scale/shift; normalized totals & trace.
__global__ __launch_bounds__(256) void bn_finalize(
    const float* __restrict__ psum, const float* __restrict__ psq,
    const float* __restrict__ ptr,
    const float* __restrict__ g, const float* __restrict__ b,
    float* __restrict__ scale, float* __restrict__ shift,
    float* __restrict__ ttl, int nblk) {
    int c = blockIdx.x, t = threadIdx.x;
    float s = 0.f, q = 0.f, tr = 0.f;
    for (int k = t; k < nblk; k += 256) { s += psum[c * 2048 + k]; q += psq[c * 2048 + k]; }
    for (int k = t; k < 512; k += 256) tr += ptr[c * 512 + k];
    for (int off = 32; off > 0; off >>= 1) {
        s += __shfl_down(s, off); q += __shfl_down(q, off); tr += __shfl_down(tr, off);
    }
    __shared__ float r1[4], r2[4], r3[4];
    if ((t & 63) == 0) { r1[t >> 6] = s; r2[t >> 6] = q; r3[t >> 6] = tr; }
    __syncthreads();
    if (t == 0) {
        s = r1[0] + r1[1] + r1[2] + r1[3];
        q = r2[0] + r2[1] + r2[2] + r2[3];
        tr = r3[0] + r3[1] + r3[2] + r3[3];
        float mean = s * (1.f / 262144.f);
        float var = q * (1.f / 262144.f) - mean * mean;
        float sc = g[c] * rsqrtf(fmaxf(var, 0.f) + 1e-5f);
        float sh = b[c] - mean * sc;
        scale[c] = sc;
        shift[c] = sh;
        ttl[64 + c] = sc * s + 262144.f * sh;   // total
        ttl[c]      = sc * tr + 512.f * sh;     // trace
    }
}

// ---------------------------------------------------------------------------
// K12a: one extractor per block (4 blocks, 256 thr). thread=(h,q): q = c-quarter.
__global__ __launch_bounds__(256) void extractor_par(
    const float* __restrict__ tt,
    const float* __restrict__ np1w, const float* __restrict__ np1b,
    const float* __restrict__ np2w, const float* __restrict__ np3w,
    const float* __restrict__ fe1w, const float* __restrict__ fe1b,
    const float* __restrict__ fe2w, const float* __restrict__ fe3w,
    float* __restrict__ oacc_part) {
    __shared__ float red[64][4];
    __shared__ float xo[64];
    const int li = blockIdx.x;
    const int t = threadIdx.x;
    const int h = t >> 2, q = t & 3;
    const int C = (li == 0) ? 32 : 64;
    const float* w1 = (li == 0) ? np1w : fe1w + (li - 1) * 4096;
    const float* b1 = (li == 0) ? np1b : fe1b + (li - 1) * 64;
    const float* w2 = (li == 0) ? np2w : fe2w + (li - 1) * 4096;
    const float* w3 = (li == 0) ? np3w : fe3w + (li - 1) * 4096;
    const float* tr = tt + li * 128;
    const float* to = tr + 64;
    const int cpq = C >> 2;
    float p = 0.f;
    for (int i = 0; i < cpq; ++i) {
        int c = q * cpq + i;
        p += (tr[c] * (1.f / 512.f)) * w1[h * C + c]
           + ((to[c] - tr[c]) * (1.f / (512.f * 511.f))) * w2[h * C + c];
    }
    red[h][q] = p;
    __syncthreads();
    if (q == 0) xo[h] = b1[h] + red[h][0] + red[h][1] + red[h][2] + red[h][3];
    __syncthreads();
    float o = xo[h];
    float p3 = 0.f;
    for (int i = 0; i < 16; ++i) {
        int f = q * 16 + i;
        p3 += fmaxf(xo[f], 0.f) * w3[h * 64 + f];
    }
    __syncthreads();
    red[h][q] = p3;
    __syncthreads();
    if (q == 0) oacc_part[li * 64 + h] = o + red[h][0] + red[h][1] + red[h][2] + red[h][3];
}

// ---------------------------------------------------------------------------
// K12b: head, 256 threads, 4-way split per output.
__global__ __launch_bounds__(256) void head_par(
    const float* __restrict__ oacc_part,
    const float* __restrict__ acw, const float* __restrict__ acb,
    const float* __restrict__ flw, const float* __restrict__ flb,
    float* __restrict__ out) {
    __shared__ float x[64], x2[64], red[64][4], l[10];
    const int t = threadIdx.x;
    const int h = t >> 2, q = t & 3;
    if (q == 0) {
        float oa = oacc_part[h] + oacc_part[64 + h] + oacc_part[128 + h] + oacc_part[192 + h];
        x[h] = fmaxf(oa, 0.f) * (1.f / 3.f);
    }
    __syncthreads();
    float p = 0.f;
    for (int i = 0; i < 16; ++i) { int f = q * 16 + i; p += x[f] * acw[h * 64 + f]; }
    red[h][q] = p;
    __syncthreads();
    if (q == 0) {
        float y = acb[h] + red[h][0] + red[h][1] + red[h][2] + red[h][3];
        x2[h] = x[h] + fmaxf(y, 0.f);
    }
    __syncthreads();
    if (t < 40) {
        int hh = t >> 2, qq = t & 3;
        float p2 = 0.f;
        for (int i = 0; i < 16; ++i) { int f = qq * 16 + i; p2 += x2[f] * flw[hh * 64 + f]; }
        red[hh][qq] = p2;
    }
    __syncthreads();
    if (t < 10) l[t] = flb[t] + red[t][0] + red[t][1] + red[t][2] + red[t][3];
    __syncthreads();
    if (t == 0) {
        float m = l[0];
        for (int i = 1; i < 10; ++i) m = fmaxf(m, l[i]);
        float se = 0.f;
        for (int i = 0; i < 10; ++i) se += expf(l[i] - m);
        float ls = m + logf(se);
        for (int i = 0; i < 10; ++i) out[i] = l[i] - ls;
    }
}

// ---------------------------------------------------------------------------
extern "C" void kernel_launch(void* const* d_in, const int* in_sizes, int n_in,
                              void* d_out, int out_size, void* d_ws, size_t ws_size,
                              hipStream_t stream) {
    float* out = (float*)d_out;

    static const int exp_sizes[28] = {
        8192, 32768,
        2048, 64, 2048, 4096,
        2048, 64, 2048, 64, 6144, 64,
        8192, 128, 8192, 128, 16384, 128,
        192, 192,
        12288, 192, 12288, 12288,
        4096, 64, 640, 10
    };
    bool ok = (n_in == 28);
    if (ok) for (int i = 0; i < 28; ++i) if (in_sizes[i] != exp_sizes[i]) ok = false;
    if (!ok) { sentinel_kernel<<<1, 64, 0, stream>>>(out, -5.0f); return; }

    const size_t RSZ = (size_t)NN * 64 * 2;            // 33.55 MB per region
    const size_t BIG_OFF = 8192 + 90112;               // control (8KB) + bf16 weight arena
    if (ws_size < BIG_OFF + 4 * RSZ) {
        sentinel_kernel<<<1, 64, 0, stream>>>(out, -7.0f);
        return;
    }

    const float* x     = (const float*)d_in[0];
    const int*   ei    = (const int*)d_in[1];
    const float* np1w  = (const float*)d_in[2];
    const float* np1b  = (const float*)d_in[3];
    const float* np2w  = (const float*)d_in[4];
    const float* np3w  = (const float*)d_in[5];
    const float* c0m1b = (const float*)d_in[7];
    const float* c0m2b = (const float*)d_in[9];
    const float* c0m4b = (const float*)d_in[11];
    const float* cm1b  = (const float*)d_in[13];
    const float* cm2b  = (const float*)d_in[15];
    const float* cm4b  = (const float*)d_in[17];
    const float* bng   = (const float*)d_in[18];
    const float* bnb   = (const float*)d_in[19];
    const float* fe1w  = (const float*)d_in[20];
    const float* fe1b  = (const float*)d_in[21];
    const float* fe2w  = (const float*)d_in[22];
    const float* fe3w  = (const float*)d_in[23];
    const float* acw   = (const float*)d_in[24];
    const float* acb   = (const float*)d_in[25];
    const float* flw   = (const float*)d_in[26];
    const float* flb   = (const float*)d_in[27];

    char* ws = (char*)d_ws;
    float* small = (float*)ws;
    float* tt    = small;          // [4][128]: per-layer trace(64)|total(64)
    float* scl   = small + 512;
    float* shf   = small + 576;
    float* oaccp = small + 640;    // [4][64] extractor partials

    u16* arena = (u16*)(ws + 8192);          // bf16 conv weights, 43008 elements

    char* big = ws + BIG_OFF;
    u16* S0 = (u16*)(big + 0 * RSZ);
    u16* S1 = (u16*)(big + 1 * RSZ);
    u16* S2 = (u16*)(big + 2 * RSZ);
    u16* S3 = (u16*)(big + 3 * RSZ);
    float* Abuf = (float*)S2;                // fp32 staging, dead after finalize_u0

    // BN partial buffers live in S2 (o2 slot) — dead between bmm and next conv12.
    float* psum = (float*)S2;                          // 64*2048
    float* psq  = psum + 64 * 2048;                    // 64*2048
    float* ptr  = psq + 64 * 2048;                     // 64*512

    hipMemsetAsync(small, 0, 4096, stream);
    hipMemsetAsync(Abuf, 0, (size_t)NN * 32 * 4, stream);

    cvt_weights<<<168, 256, 0, stream>>>((const float*)d_in[6], (const float*)d_in[8],
                                         (const float*)d_in[10], (const float*)d_in[12],
                                         (const float*)d_in[14], (const float*)d_in[16], arena);
    scatter_edges<<<2048, 256, 0, stream>>>(x, ei, Abuf);
    finalize_u0<<<1024, 256, 0, stream>>>(Abuf, S0, tt + 64);        // total -> tt[0][64..]
    trace_raw_cm<<<32, 256, 0, stream>>>(S0, tt);                    // trace -> tt[0][0..31]

    u16* U[3]  = { S0, S1, S0 };
    u16* O1[3] = { S1, S0, S1 };
    u16* R[3]  = { S1, S0, S1 };

    const float *aff_s = nullptr, *aff_h = nullptr;

    for (int l = 0; l < 3; ++l) {
        int Cin = (l == 0) ? 32 : 64;
        const u16 *w1b, *w2b, *w4b;
        const float *b1, *b2, *b4;
        if (l == 0) {
            w1b = arena;            b1 = c0m1b;
            w2b = arena + 2048;     b2 = c0m2b;
            w4b = arena + 4096;     b4 = c0m4b;
        } else {
            int m = l - 1;
            w1b = arena + 10240 + m * 4096;  b1 = cm1b + m * 64;
            w2b = arena + 18432 + m * 4096;  b2 = cm2b + m * 64;
            w4b = arena + 26624 + m * 8192;  b4 = cm4b + m * 64;
        }
        if (Cin == 32)
            conv12_s<32><<<512, 512, 0, stream>>>(U[l], aff_s, aff_h, w1b, b1, w2b, b2, O1[l], S2);
        else
            conv12_s<64><<<512, 512, 0, stream>>>(U[l], aff_s, aff_h, w1b, b1, w2b, b2, O1[l], S2);
        bmm_mfma256<<<256, 512, 0, stream>>>(O1[l], S2, S3);
        int nblk;
        if (Cin == 32) {
            conv4_t<3><<<2048, 256, 0, stream>>>(S3, U[l], aff_s, aff_h, w4b, b4, R[l], psum, psq, ptr);
            nblk = 2048;
        } else {
            conv4_s<<<512, 512, 0, stream>>>(S3, U[l], aff_s, aff_h, w4b, b4, R[l], psum, psq, ptr);
            nblk = 512;
        }
        bn_finalize<<<64, 256, 0, stream>>>(psum, psq, ptr, bng + l * 64, bnb + l * 64,
                                            scl, shf, tt + (l + 1) * 128, nblk);
        aff_s = scl; aff_h = shf;
    }
    extractor_par<<<4, 256, 0, stream>>>(tt, np1w, np1b, np2w, np3w,
                                         fe1w, fe1b, fe2w, fe3w, oaccp);
    head_par<<<1, 256, 0, stream>>>(oaccp, acw, acb, flw, flb, out);
}

// Round 9
// 488.986 us; speedup vs baseline: 1.0863x; 1.0863x over previous
//
#include <hip/hip_runtime.h>
#include <hip/hip_bf16.h>

// Problem dims (fixed)
#define Nn   512
#define NN   262144        // N*N positions
#define EDG  16384

typedef unsigned short u16;
typedef unsigned int u32;
typedef short v8s __attribute__((ext_vector_type(8)));   // 8 bf16 lanes (4 VGPR)
typedef float v4f __attribute__((ext_vector_type(4)));
typedef u16 u16x8 __attribute__((ext_vector_type(8)));

__device__ __forceinline__ float b2f(u16 u) {
    union { unsigned int i; float f; } v; v.i = ((unsigned int)u) << 16; return v.f;
}
__device__ __forceinline__ u16 f2b(float f) {
    union { float f; unsigned int i; } v; v.f = f;
    unsigned int r = (v.i + 0x7FFFu + ((v.i >> 16) & 1u)) >> 16;
    return (u16)r;
}
// affine on a packed pair of bf16 (2 positions of one channel)
__device__ __forceinline__ u32 aff2(u32 x, float s, float h) {
    float lo = b2f((u16)(x & 0xFFFFu)) * s + h;
    float hi = b2f((u16)(x >> 16)) * s + h;
    return (u32)f2b(lo) | ((u32)f2b(hi) << 16);
}

// ---------------------------------------------------------------------------
__global__ void sentinel_kernel(float* __restrict__ out, float val) {
    if (threadIdx.x < 10) out[threadIdx.x] = val;
}

// ---------------------------------------------------------------------------
// K0: convert the 6 conv weight tensors (fp32) into one bf16 arena.
__global__ void cvt_weights(const float* __restrict__ s0, const float* __restrict__ s1,
                            const float* __restrict__ s2, const float* __restrict__ s3,
                            const float* __restrict__ s4, const float* __restrict__ s5,
                            u16* __restrict__ dst) {
    int t = blockIdx.x * 256 + threadIdx.x;
    if (t >= 43008) return;
    float v;
    if      (t < 2048)  v = s0[t];
    else if (t < 4096)  v = s1[t - 2048];
    else if (t < 10240) v = s2[t - 4096];
    else if (t < 18432) v = s3[t - 10240];
    else if (t < 26624) v = s4[t - 18432];
    else                v = s5[t - 26624];
    dst[t] = f2b(v);
}

// ---------------------------------------------------------------------------
// K1: scatter edges into A (fp32, pos-major [p][32]); x is fp32 [512][16]
__global__ void scatter_edges(const float* __restrict__ x, const int* __restrict__ ei,
                              float* __restrict__ A) {
    int t = blockIdx.x * 256 + threadIdx.x;
    if (t >= EDG * 32) return;
    int e = t >> 5, c = t & 31;
    int s = ei[e], d = ei[EDG + e];
    float v = (c < 16) ? x[s * 16 + c] : x[d * 16 + (c - 16)];
    atomicAdd(A + ((size_t)s * Nn + d) * 32 + c, v);
}

// ---------------------------------------------------------------------------
// K2: A fp32 pos-major [p][32] -> u0 CHANNEL-MAJOR bf16 [32][NN]; totals into tt0[64..]
__global__ __launch_bounds__(256) void finalize_u0(const float* __restrict__ A,
                                                   u16* __restrict__ u0,
                                                   float* __restrict__ total) {
    __shared__ u16 L[32 * 258];
    __shared__ float red[4][32];
    int t = threadIdx.x;
    int p0 = blockIdx.x * 256;
    const float* Ar = A + (size_t)(p0 + t) * 32;
    float v[32];
#pragma unroll
    for (int c = 0; c < 32; ++c) v[c] = Ar[c];
#pragma unroll
    for (int c = 0; c < 32; ++c) L[c * 258 + t] = f2b(v[c]);
    int wv = t >> 6;
#pragma unroll
    for (int c = 0; c < 32; ++c) {
        float r = v[c];
        for (int off = 32; off > 0; off >>= 1) r += __shfl_down(r, off);
        if ((t & 63) == 0) red[wv][c] = r;
    }
    __syncthreads();
    if (t < 32) atomicAdd(total + t, red[0][t] + red[1][t] + red[2][t] + red[3][t]);
    int off = (t & 31) * 8, rb = t >> 5;
#pragma unroll
    for (int pass = 0; pass < 4; ++pass) {
        int c = pass * 8 + rb;
        u16x8 w = *(const u16x8*)(L + c * 258 + off);
        *(u16x8*)(u0 + (size_t)c * NN + p0 + off) = w;
    }
}

// ---------------------------------------------------------------------------
// K3: trace of channel-major activation; grid = C blocks.
__global__ void trace_raw_cm(const u16* __restrict__ ucm, float* __restrict__ trraw) {
    int c = blockIdx.x, t = threadIdx.x;
    const u16* base = ucm + (size_t)c * NN;
    float s = b2f(base[(size_t)(2 * t) * 513]) + b2f(base[(size_t)(2 * t + 1) * 513]);
    for (int off = 32; off > 0; off >>= 1) s += __shfl_down(s, off);
    __shared__ float r[4];
    if ((t & 63) == 0) r[t >> 6] = s;
    __syncthreads();
    if (t == 0) trraw[c] = r[0] + r[1] + r[2] + r[3];
}

// ---------------------------------------------------------------------------
// K5 v2.1: streaming conv1+conv2. Grid 512 x 512 thr, 4 tiles of 128
// positions per block; weights in registers; pack-transpose LDS staging.
// Epilogue: PLAIN scalar u16 stores (r7 post-mortem: nontemporal + partial-
// line segments caused 3-4x write amplification; bmm's plain scalar stores
// measure 1.13x).
template<int CIN>
__global__ __launch_bounds__(512, 4) void conv12_s(
    const u16* __restrict__ src,
    const float* __restrict__ sc, const float* __restrict__ sh,
    const u16* __restrict__ w1, const float* __restrict__ b1,
    const u16* __restrict__ w2, const float* __restrict__ b2,
    u16* __restrict__ dst1, u16* __restrict__ dst2)
{
    constexpr int G    = CIN / 8;            // 16B granules per position row
    constexpr int LOGG = (CIN == 64) ? 3 : 2;
    constexpr int ROWB = CIN * 2;            // bytes per position row
    constexpr int KC   = CIN / 32;
    constexpr int PASSES = CIN / 32;         // stage passes (512 u32-units each)

    __shared__ char LB[2][128 * ROWB];

    const int t = threadIdx.x;
    const int lane = t & 63, w = t >> 6;
    const int l15 = lane & 15, quad = lane >> 4;
    const int wr = w >> 1;                   // 4 M-groups of 32 rows
    const int wn = w & 1;                    // 2 N-groups of 64 positions
    const size_t Pblk = (size_t)blockIdx.x * 512;

    // ---- stage-role mapping (flat threads)
    const int cpair = (CIN == 64) ? (t >> 4) : (t >> 5);   // channel pair index
    const int pg    = (CIN == 64) ? (t & 15) : (t & 31);   // 4-position group
    const int g0    = cpair >> 2;
    const int word  = cpair & 3;
    const u16* srcA = src + (size_t)(2 * cpair) * NN;
    float s0 = 1.f, h0 = 0.f, s1 = 1.f, h1 = 0.f;
    const bool aff = (sc != nullptr);
    if (aff) { s0 = sc[2 * cpair]; h0 = sh[2 * cpair]; s1 = sc[2 * cpair + 1]; h1 = sh[2 * cpair + 1]; }

    // ---- weights in registers: stacked rows [w1; w2], this wave owns 32 rows
    v8s af[2][KC];
#pragma unroll
    for (int mt = 0; mt < 2; ++mt) {
        const int row = wr * 32 + mt * 16 + l15;
        const u16* Wm = (row < 64) ? (w1 + row * CIN) : (w2 + (row - 64) * CIN);
#pragma unroll
        for (int kc = 0; kc < KC; ++kc)
            af[mt][kc] = *(const v8s*)(Wm + kc * 32 + quad * 8);
    }
    float bias[2][4];
#pragma unroll
    for (int mt = 0; mt < 2; ++mt)
#pragma unroll
        for (int r = 0; r < 4; ++r) {
            const int row = wr * 32 + mt * 16 + quad * 4 + r;
            bias[mt][r] = (row < 64) ? b1[row] : b2[row - 64];
        }

    v4f acc[2][4];
#pragma unroll
    for (int mt = 0; mt < 2; ++mt)
#pragma unroll
        for (int nt = 0; nt < 4; ++nt) acc[mt][nt] = (v4f){0.f, 0.f, 0.f, 0.f};

    uint2 ea[PASSES], eb[PASSES];

#define C12_LOAD(T)                                                           \
    _Pragma("unroll")                                                         \
    for (int pp = 0; pp < PASSES; ++pp) {                                     \
        const int p0_ = (pg + ((CIN == 64) ? 16 : 0) * pp) * 4;               \
        const u16* sp_ = srcA + Pblk + (size_t)(T) * 128 + p0_;               \
        ea[pp] = *(const uint2*)sp_;                                          \
        eb[pp] = *(const uint2*)(sp_ + NN);                                   \
    }

#define C12_WRITE(BUF)                                                        \
    {                                                                         \
        char* Lb_ = LB[BUF];                                                  \
        _Pragma("unroll")                                                     \
        for (int pp = 0; pp < PASSES; ++pp) {                                 \
            const int p0_ = (pg + ((CIN == 64) ? 16 : 0) * pp) * 4;           \
            u32 A0 = ea[pp].x, A1 = ea[pp].y, B0 = eb[pp].x, B1 = eb[pp].y;   \
            if (aff) {                                                        \
                A0 = aff2(A0, s0, h0); A1 = aff2(A1, s0, h0);                 \
                B0 = aff2(B0, s1, h1); B1 = aff2(B1, s1, h1);                 \
            }                                                                 \
            u32 pk0 = (A0 & 0xFFFFu) | (B0 << 16);                            \
            u32 pk1 = (A0 >> 16) | (B0 & 0xFFFF0000u);                        \
            u32 pk2 = (A1 & 0xFFFFu) | (B1 << 16);                            \
            u32 pk3 = (A1 >> 16) | (B1 & 0xFFFF0000u);                        \
            _Pragma("unroll")                                                 \
            for (int w4 = 0; w4 < 4; ++w4) {                                  \
                const int p_ = p0_ + w4;                                      \
                const int g_ = g0 ^ (p_ & (G - 1)) ^ ((p_ >> LOGG) & (G - 1));\
                u32 v_ = (w4 == 0) ? pk0 : (w4 == 1) ? pk1 : (w4 == 2) ? pk2 : pk3; \
                *(u32*)(Lb_ + p_ * ROWB + g_ * 16 + word * 4) = v_;           \
            }                                                                 \
        }                                                                     \
    }

#define C12_COMPUTE(BUF)                                                      \
    _Pragma("unroll")                                                         \
    for (int kc = 0; kc < KC; ++kc) {                                         \
        v8s bf_[4];                                                           \
        const char* Lb_ = LB[BUF];                                            \
        _Pragma("unroll")                                                     \
        for (int nt = 0; nt < 4; ++nt) {                                      \
            const int p_ = wn * 64 + nt * 16 + l15;                           \
            const int lg_ = kc * 4 + quad;                                    \
            const int g_ = lg_ ^ (p_ & (G - 1)) ^ ((p_ >> LOGG) & (G - 1));   \
            bf_[nt] = *(const v8s*)(Lb_ + p_ * ROWB + g_ * 16);               \
        }                                                                     \
        _Pragma("unroll")                                                     \
        for (int mt = 0; mt < 2; ++mt)                                        \
            _Pragma("unroll")                                                 \
            for (int nt = 0; nt < 4; ++nt)                                    \
                acc[mt][nt] = __builtin_amdgcn_mfma_f32_16x16x32_bf16(        \
                    af[mt][kc], bf_[nt], acc[mt][nt], 0, 0, 0);               \
    }

    // ---- prologue
    C12_LOAD(0)
    C12_WRITE(0)
    __syncthreads();

#pragma unroll
    for (int T = 0; T < 4; ++T) {
        const int cur = T & 1;
        if (T < 3) C12_LOAD(T + 1)
        C12_COMPUTE(cur)
        // epilogue: direct channel-major stores (plain, L2 write-combined)
#pragma unroll
        for (int mt = 0; mt < 2; ++mt)
#pragma unroll
            for (int r = 0; r < 4; ++r) {
                const int row = wr * 32 + mt * 16 + quad * 4 + r;
                u16* dp = ((row < 64) ? (dst1 + (size_t)row * NN)
                                      : (dst2 + (size_t)(row - 64) * NN))
                          + Pblk + (size_t)T * 128 + wn * 64 + l15;
#pragma unroll
                for (int nt = 0; nt < 4; ++nt) {
                    dp[nt * 16] = f2b(acc[mt][nt][r] + bias[mt][r]);
                }
            }
        // acc reset for next tile
#pragma unroll
        for (int mt = 0; mt < 2; ++mt)
#pragma unroll
            for (int nt = 0; nt < 4; ++nt) acc[mt][nt] = (v4f){0.f,0.f,0.f,0.f};
        if (T < 3) {
            C12_WRITE(cur ^ 1)
            __syncthreads();
        }
    }
#undef C12_LOAD
#undef C12_WRITE
#undef C12_COMPUTE
}

// ---------------------------------------------------------------------------
// K6 v2.1: streaming m4 conv for K=128 (layers 1-2). Same as r7 but with
// PLAIN epilogue stores (nontemporal scalar stores caused 4.2x write amp +
// RMW fetches — r7 counters: WRITE 145MB vs ideal 34.7, FETCH 111 vs 67).
__global__ __launch_bounds__(512, 6) void conv4_s(
    const u16* __restrict__ mult, const u16* __restrict__ u,
    const float* __restrict__ sc, const float* __restrict__ sh,
    const u16* __restrict__ w, const float* __restrict__ bias,
    u16* __restrict__ dst,
    float* __restrict__ psum, float* __restrict__ psq, float* __restrict__ ptr)
{
    constexpr int ROWB = 256;                // 128 ch * 2B
    __shared__ char IN[128 * ROWB];          // 32 KB single buffer
    __shared__ float R1[64][2], R2[64][2];

    const int t = threadIdx.x;
    const int lane = t & 63, w8 = t >> 6;
    const int l15 = lane & 15, quad = lane >> 4;
    const int wq = w8 >> 1;                  // 4 row-groups of 16
    const int wn = w8 & 1;                   // 2 pos-halves of 64
    const int brow = blockIdx.x;             // block owns matrix row brow
    const size_t Pblk = (size_t)brow * 512;

    // stage mapping: 64 channel-pairs x 8 pos-groups, 4 position passes
    const int pair = t >> 3;
    const int pg = t & 7;
    const int g0 = pair >> 2;
    const int word = pair & 3;
    const bool isU = pair >= 32;
    const u16* srcA = isU ? (u + (size_t)(2 * pair - 64) * NN)
                          : (mult + (size_t)(2 * pair) * NN);
    float s0 = 1.f, h0 = 0.f, s1 = 1.f, h1 = 0.f;
    const bool doaff = isU && (sc != nullptr);
    if (doaff) { s0 = sc[2 * pair - 64]; h0 = sh[2 * pair - 64];
                 s1 = sc[2 * pair - 63]; h1 = sh[2 * pair - 63]; }

    // weights + bias in registers: this wave-group owns rows wq*16..wq*16+15
    v8s af[4];
#pragma unroll
    for (int kc = 0; kc < 4; ++kc)
        af[kc] = *(const v8s*)(w + (wq * 16 + l15) * 128 + kc * 32 + quad * 8);
    float bv_[4];
#pragma unroll
    for (int r = 0; r < 4; ++r)
        bv_[r] = bias[wq * 16 + quad * 4 + r];

    v4f acc[4];
    float bnS[4], bnQ[4];
#pragma unroll
    for (int nt = 0; nt < 4; ++nt) acc[nt] = (v4f){0.f, 0.f, 0.f, 0.f};
#pragma unroll
    for (int r = 0; r < 4; ++r) { bnS[r] = 0.f; bnQ[r] = 0.f; }

    uint2 ea[4], eb[4];

#define C4_LOAD(T)                                                            \
    _Pragma("unroll")                                                         \
    for (int pp = 0; pp < 4; ++pp) {                                          \
        const int p0_ = (pg + 8 * pp) * 4;                                    \
        const u16* sp_ = srcA + Pblk + (size_t)(T) * 128 + p0_;               \
        ea[pp] = *(const uint2*)sp_;                                          \
        eb[pp] = *(const uint2*)(sp_ + NN);                                   \
    }

#define C4_WRITE()                                                            \
    {                                                                         \
        _Pragma("unroll")                                                     \
        for (int pp = 0; pp < 4; ++pp) {                                      \
            const int p0_ = (pg + 8 * pp) * 4;                                \
            u32 A0 = ea[pp].x, A1 = ea[pp].y, B0 = eb[pp].x, B1 = eb[pp].y;   \
            if (doaff) {                                                      \
                A0 = aff2(A0, s0, h0); A1 = aff2(A1, s0, h0);                 \
                B0 = aff2(B0, s1, h1); B1 = aff2(B1, s1, h1);                 \
            }                                                                 \
            u32 pk0 = (A0 & 0xFFFFu) | (B0 << 16);                            \
            u32 pk1 = (A0 >> 16) | (B0 & 0xFFFF0000u);                        \
            u32 pk2 = (A1 & 0xFFFFu) | (B1 << 16);                            \
            u32 pk3 = (A1 >> 16) | (B1 & 0xFFFF0000u);                        \
            _Pragma("unroll")                                                 \
            for (int w4 = 0; w4 < 4; ++w4) {                                  \
                const int p_ = p0_ + w4;                                      \
                const int g_ = g0 ^ (p_ & 15) ^ ((p_ >> 4) & 15);             \
                u32 v_ = (w4 == 0) ? pk0 : (w4 == 1) ? pk1 : (w4 == 2) ? pk2 : pk3; \
                *(u32*)(IN + p_ * ROWB + g_ * 16 + word * 4) = v_;            \
            }                                                                 \
        }                                                                     \
    }

#define C4_COMPUTE()                                                          \
    _Pragma("unroll")                                                         \
    for (int kc = 0; kc < 4; ++kc) {                                          \
        v8s bf_[4];                                                           \
        _Pragma("unroll")                                                     \
        for (int nt = 0; nt < 4; ++nt) {                                      \
            const int p_ = wn * 64 + nt * 16 + l15;                           \
            const int lg_ = kc * 4 + quad;                                    \
            const int g_ = lg_ ^ (p_ & 15) ^ ((p_ >> 4) & 15);                \
            bf_[nt] = *(const v8s*)(IN + p_ * ROWB + g_ * 16);                \
        }                                                                     \
        _Pragma("unroll")                                                     \
        for (int nt = 0; nt < 4; ++nt)                                        \
            acc[nt] = __builtin_amdgcn_mfma_f32_16x16x32_bf16(                \
                af[kc], bf_[nt], acc[nt], 0, 0, 0);                           \
    }

    // ---- prologue
    C4_LOAD(0)
    C4_WRITE()
    __syncthreads();

#pragma unroll
    for (int T = 0; T < 4; ++T) {
        if (T < 3) C4_LOAD(T + 1)
        C4_COMPUTE()
        __syncthreads();                     // all done reading IN
        if (T < 3) C4_WRITE()                // regs -> IN (next tile)
        // epilogue: plain channel-major stores + BN accum + trace pick
#pragma unroll
        for (int r = 0; r < 4; ++r) {
            const int c = wq * 16 + quad * 4 + r;
            u16* dp = dst + (size_t)c * NN + Pblk + (size_t)T * 128 + wn * 64 + l15;
#pragma unroll
            for (int nt = 0; nt < 4; ++nt) {
                const int pos = T * 128 + wn * 64 + nt * 16 + l15;
                float fv = acc[nt][r] + bv_[r];
                u16 b16 = f2b(fv);
                float rv = b2f(b16);
                bnS[r] += rv;
                bnQ[r] += rv * rv;
                dp[nt * 16] = b16;
                if (pos == brow) ptr[c * 512 + brow] = rv;
            }
        }
#pragma unroll
        for (int nt = 0; nt < 4; ++nt) acc[nt] = (v4f){0.f, 0.f, 0.f, 0.f};
        if (T < 3) __syncthreads();          // IN ready for next compute
    }

    // ---- BN partial reduction: 16-lane butterfly, then across the 2 wn waves
#pragma unroll
    for (int r = 0; r < 4; ++r) {
        float s = bnS[r], q = bnQ[r];
#pragma unroll
        for (int m = 1; m < 16; m <<= 1) {
            s += __shfl_xor(s, m);
            q += __shfl_xor(q, m);
        }
        if (l15 == 0) {
            const int c = wq * 16 + quad * 4 + r;
            R1[c][wn] = s; R2[c][wn] = q;
        }
    }
    __syncthreads();
    if (t < 64) {
        psum[t * 2048 + brow] = R1[t][0] + R1[t][1];
        psq[t * 2048 + brow]  = R2[t][0] + R2[t][1];
    }
#undef C4_LOAD
#undef C4_WRITE
#undef C4_COMPUTE
}

// ---------------------------------------------------------------------------
// K6: m4 conv (r9, proven) — kept for layer 0 (K=96). Full-line u16x8 nt
// stores (fine).
template<int NCH>
__global__ __launch_bounds__(256) void conv4_t(
    const u16* __restrict__ mult, const u16* __restrict__ u,
    const float* __restrict__ sc, const float* __restrict__ sh,
    const u16* __restrict__ w, const float* __restrict__ bias,
    u16* __restrict__ dst,
    float* __restrict__ psum, float* __restrict__ psq, float* __restrict__ ptr)
{
    __shared__ u16 LS[8320];
    __shared__ float R1[64][4], R2[64][4];
    const int K = NCH * 32;
    const int t = threadIdx.x;
    const int P0 = blockIdx.x * 128;
    const int lane = t & 63, wave = t >> 6;
    const int l15 = lane & 15, quad = lane >> 4;
    const int pw = wave * 32;
    const int sr = t >> 4;
    const int so = (t & 15) * 8;

    u16x8 pf[NCH][2];
#pragma unroll
    for (int kc = 0; kc < NCH; ++kc)
#pragma unroll
        for (int ps = 0; ps < 2; ++ps) {
            int cg = kc * 32 + ps * 16 + sr;
            const u16* gp = (cg < 64) ? (mult + (size_t)cg * NN + P0 + so)
                                      : (u + (size_t)(cg - 64) * NN + P0 + so);
            pf[kc][ps] = *(const u16x8*)gp;
        }

    v4f acc[4][2];
#pragma unroll
    for (int mt = 0; mt < 4; ++mt)
#pragma unroll
        for (int nt = 0; nt < 2; ++nt) acc[mt][nt] = (v4f){0.f, 0.f, 0.f, 0.f};

#pragma unroll
    for (int ps = 0; ps < 2; ++ps)
        *(u16x8*)(LS + (ps * 16 + sr) * 130 + so) = pf[0][ps];
    __syncthreads();
#pragma unroll
    for (int kc = 0; kc < NCH; ++kc) {
        if (kc + 1 < NCH) {
            u16* Ln = LS + ((kc + 1) & 1) * 4160;
#pragma unroll
            for (int ps = 0; ps < 2; ++ps) {
                int c = ps * 16 + sr;
                int cg = (kc + 1) * 32 + c;
                u16x8 v = pf[kc + 1][ps];
                if (cg >= 64 && sc) {
                    float s = sc[cg - 64], f = sh[cg - 64];
#pragma unroll
                    for (int j = 0; j < 8; ++j) v[j] = f2b(b2f(v[j]) * s + f);
                }
                *(u16x8*)(Ln + c * 130 + so) = v;
            }
        }
        v8s af[4];
#pragma unroll
        for (int mt = 0; mt < 4; ++mt)
            af[mt] = *(const v8s*)(w + (mt * 16 + l15) * K + kc * 32 + quad * 8);
        const u16* Lb = LS + (kc & 1) * 4160;
#pragma unroll
        for (int nt = 0; nt < 2; ++nt) {
            const int p = pw + nt * 16 + l15;
            v8s b;
#pragma unroll
            for (int j = 0; j < 8; ++j) b[j] = (short)Lb[(quad * 8 + j) * 130 + p];
#pragma unroll
            for (int mt = 0; mt < 4; ++mt)
                acc[mt][nt] = __builtin_amdgcn_mfma_f32_16x16x32_bf16(af[mt], b, acc[mt][nt], 0, 0, 0);
        }
        if (kc + 1 < NCH) __syncthreads();
    }
    __syncthreads();
#pragma unroll
    for (int mt = 0; mt < 4; ++mt)
#pragma unroll
        for (int r = 0; r < 4; ++r) {
            const int h = mt * 16 + quad * 4 + r;
            const float bv = bias[h];
#pragma unroll
            for (int nt = 0; nt < 2; ++nt)
                LS[h * 130 + pw + nt * 16 + l15] = f2b(acc[mt][nt][r] + bv);
        }
    __syncthreads();
    {
        int c = t >> 2, q = t & 3;
        const u16* row = LS + c * 130 + q * 32;
        float s = 0.f, s2 = 0.f;
#pragma unroll
        for (int i = 0; i < 32; ++i) { float v = b2f(row[i]); s += v; s2 += v * v; }
        R1[c][q] = s; R2[c][q] = s2;
    }
    __syncthreads();
    {
        int i = P0 >> 9, j0 = P0 & 511;
        int blk = blockIdx.x;
        if (t < 64) {
            psum[t * 2048 + blk] = R1[t][0] + R1[t][1] + R1[t][2] + R1[t][3];
            psq[t * 2048 + blk]  = R2[t][0] + R2[t][1] + R2[t][2] + R2[t][3];
            if (j0 <= i && i < j0 + 128) ptr[t * 512 + i] = b2f(LS[t * 130 + (i - j0)]);
        }
    }
#pragma unroll
    for (int ps = 0; ps < 4; ++ps) {
        int h = ps * 16 + sr;
        u16x8 v = *(const u16x8*)(LS + h * 130 + so);
        __builtin_nontemporal_store(v, (u16x8*)(dst + (size_t)h * NN + P0 + so));
    }
}

// ---------------------------------------------------------------------------
// K7 v5: batched per-channel GEMM, 256x256 tile, 8 waves (verified r1).
__global__ __launch_bounds__(512, 2) void bmm_mfma256(const u16* __restrict__ Aall,
                                                      const u16* __restrict__ Ball,
                                                      u16* __restrict__ Call) {
    __shared__ u16 LA[2][16384];   // [buf][256 rows][64 k]  (granule-swizzled)
    __shared__ u16 LB[2][16384];   // [buf][256 cols j][64 k] (transposed, swizzled)

    const int bid = blockIdx.x;
    const int h  = ((bid >> 5) << 3) | (bid & 7);   // channel; XCD = h&7
    const int qq = (bid >> 3) & 3;
    const int ty = qq >> 1, tx = qq & 1;
    const int t = threadIdx.x;
    const int l = t & 63, w = t >> 6;
    const int l15 = l & 15, quad = l >> 4;
    const int wr = w >> 2, wc = w & 3;              // 2x4 wave grid

    const u16* Ap = Aall + (size_t)h * NN + (size_t)ty * 256 * 512;
    const u16* Bp = Ball + (size_t)h * NN + tx * 256;
    u16* Cp = Call + (size_t)h * NN;

    const int a_m = l >> 3;
    const int a_kg = (l & 7) ^ a_m;
    const u16* ApL = Ap + (size_t)a_m * 512 + a_kg * 8;   // + cc*4096 + k0

    v4f acc[8][4];
#pragma unroll
    for (int mt = 0; mt < 8; ++mt)
#pragma unroll
        for (int nt = 0; nt < 4; ++nt) acc[mt][nt] = (v4f){0.f, 0.f, 0.f, 0.f};

    uint2 eB[4], oB[4];

#define BMM_BLOAD(K0)                                                         \
    _Pragma("unroll")                                                         \
    for (int L = 0; L < 4; ++L) {                                             \
        const int p = w + 8 * L;                                              \
        const u16* s_ = Bp + (size_t)((K0) + 2 * p) * 512 + l * 4;            \
        eB[L] = *(const uint2*)s_;                                            \
        oB[L] = *(const uint2*)(s_ + 512);                                    \
    }

#define BMM_ALOAD(BUF, K0)                                                    \
    _Pragma("unroll")                                                         \
    for (int c = 0; c < 4; ++c) {                                             \
        const int cc = w * 4 + c;                                             \
        __builtin_amdgcn_global_load_lds(                                     \
            (const void*)(ApL + (size_t)cc * 4096 + (K0)),                    \
            (void*)&LA[BUF][cc * 512], 16, 0, 0);                             \
    }

#define BMM_BWRITE(BUF)                                                       \
    {                                                                         \
        char* base_ = (char*)&LB[BUF][0];                                     \
        _Pragma("unroll")                                                     \
        for (int L = 0; L < 4; ++L) {                                         \
            const int p = w + 8 * L;                                          \
            const int gk = p >> 2, wd = p & 3;                                \
            u32 e0 = eB[L].x, e1 = eB[L].y, o0 = oB[L].x, o1 = oB[L].y;       \
            u32 pk0 = (e0 & 0xFFFFu) | (o0 << 16);                            \
            u32 pk1 = (e0 >> 16) | (o0 & 0xFFFF0000u);                        \
            u32 pk2 = (e1 & 0xFFFFu) | (o1 << 16);                            \
            u32 pk3 = (e1 >> 16) | (o1 & 0xFFFF0000u);                        \
            _Pragma("unroll")                                                 \
            for (int q = 0; q < 4; ++q) {                                     \
                const int j = l * 4 + q;                                      \
                const int g = gk ^ (j & 7) ^ ((j >> 3) & 7);                  \
                u32 v_ = (q == 0) ? pk0 : (q == 1) ? pk1 : (q == 2) ? pk2 : pk3; \
                *(u32*)(base_ + j * 128 + (g << 4) + wd * 4) = v_;            \
            }                                                                 \
        }                                                                     \
    }

#define BMM_COMPUTE(BUF)                                                      \
    _Pragma("unroll")                                                         \
    for (int kk = 0; kk < 2; ++kk) {                                          \
        v8s af_[8], bf_[4];                                                   \
        const char* baseA_ = (const char*)&LA[BUF][0];                        \
        const char* baseB_ = (const char*)&LB[BUF][0];                        \
        _Pragma("unroll")                                                     \
        for (int mt = 0; mt < 8; ++mt) {                                      \
            const int m = wr * 128 + mt * 16 + l15;                           \
            const int g = (kk * 4 + quad) ^ (m & 7);                          \
            af_[mt] = *(const v8s*)(baseA_ + m * 128 + (g << 4));             \
        }                                                                     \
        _Pragma("unroll")                                                     \
        for (int nt = 0; nt < 4; ++nt) {                                      \
            const int j = wc * 64 + nt * 16 + l15;                            \
            const int g = (kk * 4 + quad) ^ (j & 7) ^ ((j >> 3) & 7);         \
            bf_[nt] = *(const v8s*)(baseB_ + j * 128 + (g << 4));             \
        }                                                                     \
        _Pragma("unroll")                                                     \
        for (int mt = 0; mt < 8; ++mt)                                        \
            _Pragma("unroll")                                                 \
            for (int nt = 0; nt < 4; ++nt)                                    \
                acc[mt][nt] = __builtin_amdgcn_mfma_f32_16x16x32_bf16(        \
                    af_[mt], bf_[nt], acc[mt][nt], 0, 0, 0);                  \
    }

    BMM_BLOAD(0)
    BMM_ALOAD(0, 0)
    BMM_BWRITE(0)
    __syncthreads();

#pragma unroll 2
    for (int ts = 0; ts < 8; ++ts) {
        const int cur = ts & 1;
        if (ts < 7) {
            BMM_BLOAD((ts + 1) * 64)
            BMM_ALOAD(cur ^ 1, (ts + 1) * 64)
        }
        BMM_COMPUTE(cur)
        if (ts < 7) {
            BMM_BWRITE(cur ^ 1)
            __syncthreads();
        }
    }

#pragma unroll
    for (int mt = 0; mt < 8; ++mt)
#pragma unroll
        for (int r = 0; r < 4; ++r) {
            const int i = ty * 256 + wr * 128 + mt * 16 + quad * 4 + r;
#pragma unroll
            for (int nt = 0; nt < 4; ++nt) {
                const int j = tx * 256 + wc * 64 + nt * 16 + l15;
                Cp[(size_t)i * 512 + j] = f2b(acc[mt][nt][r]);
            }
        }
#undef BMM_BLOAD
#undef BMM_ALOAD
#undef BMM_BWRITE
#undef BMM_COMPUTE
}

// ---------------------------------------------------------------------------
// K11: reduce per-block partials; BN scale/shift; normalized totals & trace.
__global__ __launch_bounds__(256) void bn_finalize(
    const float* __restrict__ psum, const float* __restrict__ psq,
    const float* __restrict__ ptr,
    const float* __restrict__ g, const float* __restrict__ b,
    float* __restrict__ scale, float* __restrict__ shift,
    float* __restrict__ ttl, int nblk) {
    int c = blockIdx.x, t = threadIdx.x;
    float s = 0.f, q = 0.f, tr = 0.f;
    for (int k = t; k < nblk; k += 256) { s += psum[c * 2048 + k]; q += psq[c * 2048 + k]; }
    for (int k = t; k < 512; k += 256) tr += ptr[c * 512 + k];
    for (int off = 32; off > 0; off >>= 1) {
        s += __shfl_down(s, off); q += __shfl_down(q, off); tr += __shfl_down(tr, off);
    }
    __shared__ float r1[4], r2[4], r3[4];
    if ((t & 63) == 0) { r1[t >> 6] = s; r2[t >> 6] = q; r3[t >> 6] = tr; }
    __syncthreads();
    if (t == 0) {
        s = r1[0] + r1[1] + r1[2] + r1[3];
        q = r2[0] + r2[1] + r2[2] + r2[3];
        tr = r3[0] + r3[1] + r3[2] + r3[3];
        float mean = s * (1.f / 262144.f);
        float var = q * (1.f / 262144.f) - mean * mean;
        float sc = g[c] * rsqrtf(fmaxf(var, 0.f) + 1e-5f);
        float sh = b[c] - mean * sc;
        scale[c] = sc;
        shift[c] = sh;
        ttl[64 + c] = sc * s + 262144.f * sh;   // total
        ttl[c]      = sc * tr + 512.f * sh;     // trace
    }
}

// ---------------------------------------------------------------------------
// K12a: one extractor per block (4 blocks, 256 thr). thread=(h,q): q = c-quarter.
__global__ __launch_bounds__(256) void extractor_par(
    const float* __restrict__ tt,
    const float* __restrict__ np1w, const float* __restrict__ np1b,
    const float* __restrict__ np2w, const float* __restrict__ np3w,
    const float* __restrict__ fe1w, const float* __restrict__ fe1b,
    const float* __restrict__ fe2w, const float* __restrict__ fe3w,
    float* __restrict__ oacc_part) {
    __shared__ float red[64][4];
    __shared__ float xo[64];
    const int li = blockIdx.x;
    const int t = threadIdx.x;
    const int h = t >> 2, q = t & 3;
    const int C = (li == 0) ? 32 : 64;
    const float* w1 = (li == 0) ? np1w : fe1w + (li - 1) * 4096;
    const float* b1 = (li == 0) ? np1b : fe1b + (li - 1) * 64;
    const float* w2 = (li == 0) ? np2w : fe2w + (li - 1) * 4096;
    const float* w3 = (li == 0) ? np3w : fe3w + (li - 1) * 4096;
    const float* tr = tt + li * 128;
    const float* to = tr + 64;
    const int cpq = C >> 2;
    float p = 0.f;
    for (int i = 0; i < cpq; ++i) {
        int c = q * cpq + i;
        p += (tr[c] * (1.f / 512.f)) * w1[h * C + c]
           + ((to[c] - tr[c]) * (1.f / (512.f * 511.f))) * w2[h * C + c];
    }
    red[h][q] = p;
    __syncthreads();
    if (q == 0) xo[h] = b1[h] + red[h][0] + red[h][1] + red[h][2] + red[h][3];
    __syncthreads();
    float o = xo[h];
    float p3 = 0.f;
    for (int i = 0; i < 16; ++i) {
        int f = q * 16 + i;
        p3 += fmaxf(xo[f], 0.f) * w3[h * 64 + f];
    }
    __syncthreads();
    red[h][q] = p3;
    __syncthreads();
    if (q == 0) oacc_part[li * 64 + h] = o + red[h][0] + red[h][1] + red[h][2] + red[h][3];
}

// ---------------------------------------------------------------------------
// K12b: head, 256 threads, 4-way split per output.
__global__ __launch_bounds__(256) void head_par(
    const float* __restrict__ oacc_part,
    const float* __restrict__ acw, const float* __restrict__ acb,
    const float* __restrict__ flw, const float* __restrict__ flb,
    float* __restrict__ out) {
    __shared__ float x[64], x2[64], red[64][4], l[10];
    const int t = threadIdx.x;
    const int h = t >> 2, q = t & 3;
    if (q == 0) {
        float oa = oacc_part[h] + oacc_part[64 + h] + oacc_part[128 + h] + oacc_part[192 + h];
        x[h] = fmaxf(oa, 0.f) * (1.f / 3.f);
    }
    __syncthreads();
    float p = 0.f;
    for (int i = 0; i < 16; ++i) { int f = q * 16 + i; p += x[f] * acw[h * 64 + f]; }
    red[h][q] = p;
    __syncthreads();
    if (q == 0) {
        float y = acb[h] + red[h][0] + red[h][1] + red[h][2] + red[h][3];
        x2[h] = x[h] + fmaxf(y, 0.f);
    }
    __syncthreads();
    if (t < 40) {
        int hh = t >> 2, qq = t & 3;
        float p2 = 0.f;
        for (int i = 0; i < 16; ++i) { int f = qq * 16 + i; p2 += x2[f] * flw[hh * 64 + f]; }
        red[hh][qq] = p2;
    }
    __syncthreads();
    if (t < 10) l[t] = flb[t] + red[t][0] + red[t][1] + red[t][2] + red[t][3];
    __syncthreads();
    if (t == 0) {
        float m = l[0];
        for (int i = 1; i < 10; ++i) m = fmaxf(m, l[i]);
        float se = 0.f;
        for (int i = 0; i < 10; ++i) se += expf(l[i] - m);
        float ls = m + logf(se);
        for (int i = 0; i < 10; ++i) out[i] = l[i] - ls;
    }
}

// ---------------------------------------------------------------------------
extern "C" void kernel_launch(void* const* d_in, const int* in_sizes, int n_in,
                              void* d_out, int out_size, void* d_ws, size_t ws_size,
                              hipStream_t stream) {
    float* out = (float*)d_out;

    static const int exp_sizes[28] = {
        8192, 32768,
        2048, 64, 2048, 4096,
        2048, 64, 2048, 64, 6144, 64,
        8192, 128, 8192, 128, 16384, 128,
        192, 192,
        12288, 192, 12288, 12288,
        4096, 64, 640, 10
    };
    bool ok = (n_in == 28);
    if (ok) for (int i = 0; i < 28; ++i) if (in_sizes[i] != exp_sizes[i]) ok = false;
    if (!ok) { sentinel_kernel<<<1, 64, 0, stream>>>(out, -5.0f); return; }

    const size_t RSZ = (size_t)NN * 64 * 2;            // 33.55 MB per region
    const size_t BIG_OFF = 8192 + 90112;               // control (8KB) + bf16 weight arena
    if (ws_size < BIG_OFF + 4 * RSZ) {
        sentinel_kernel<<<1, 64, 0, stream>>>(out, -7.0f);
        return;
    }

    const float* x     = (const float*)d_in[0];
    const int*   ei    = (const int*)d_in[1];
    const float* np1w  = (const float*)d_in[2];
    const float* np1b  = (const float*)d_in[3];
    const float* np2w  = (const float*)d_in[4];
    const float* np3w  = (const float*)d_in[5];
    const float* c0m1b = (const float*)d_in[7];
    const float* c0m2b = (const float*)d_in[9];
    const float* c0m4b = (const float*)d_in[11];
    const float* cm1b  = (const float*)d_in[13];
    const float* cm2b  = (const float*)d_in[15];
    const float* cm4b  = (const float*)d_in[17];
    const float* bng   = (const float*)d_in[18];
    const float* bnb   = (const float*)d_in[19];
    const float* fe1w  = (const float*)d_in[20];
    const float* fe1b  = (const float*)d_in[21];
    const float* fe2w  = (const float*)d_in[22];
    const float* fe3w  = (const float*)d_in[23];
    const float* acw   = (const float*)d_in[24];
    const float* acb   = (const float*)d_in[25];
    const float* flw   = (const float*)d_in[26];
    const float* flb   = (const float*)d_in[27];

    char* ws = (char*)d_ws;
    float* small = (float*)ws;
    float* tt    = small;          // [4][128]: per-layer trace(64)|total(64)
    float* scl   = small + 512;
    float* shf   = small + 576;
    float* oaccp = small + 640;    // [4][64] extractor partials

    u16* arena = (u16*)(ws + 8192);          // bf16 conv weights, 43008 elements

    char* big = ws + BIG_OFF;
    u16* S0 = (u16*)(big + 0 * RSZ);
    u16* S1 = (u16*)(big + 1 * RSZ);
    u16* S2 = (u16*)(big + 2 * RSZ);
    u16* S3 = (u16*)(big + 3 * RSZ);
    float* Abuf = (float*)S2;                // fp32 staging, dead after finalize_u0

    // BN partial buffers live in S2 (o2 slot) — dead between bmm and next conv12.
    float* psum = (float*)S2;                          // 64*2048
    float* psq  = psum + 64 * 2048;                    // 64*2048
    float* ptr  = psq + 64 * 2048;                     // 64*512

    hipMemsetAsync(small, 0, 4096, stream);
    hipMemsetAsync(Abuf, 0, (size_t)NN * 32 * 4, stream);

    cvt_weights<<<168, 256, 0, stream>>>((const float*)d_in[6], (const float*)d_in[8],
                                         (const float*)d_in[10], (const float*)d_in[12],
                                         (const float*)d_in[14], (const float*)d_in[16], arena);
    scatter_edges<<<2048, 256, 0, stream>>>(x, ei, Abuf);
    finalize_u0<<<1024, 256, 0, stream>>>(Abuf, S0, tt + 64);        // total -> tt[0][64..]
    trace_raw_cm<<<32, 256, 0, stream>>>(S0, tt);                    // trace -> tt[0][0..31]

    u16* U[3]  = { S0, S1, S0 };
    u16* O1[3] = { S1, S0, S1 };
    u16* R[3]  = { S1, S0, S1 };

    const float *aff_s = nullptr, *aff_h = nullptr;

    for (int l = 0; l < 3; ++l) {
        int Cin = (l == 0) ? 32 : 64;
        const u16 *w1b, *w2b, *w4b;
        const float *b1, *b2, *b4;
        if (l == 0) {
            w1b = arena;            b1 = c0m1b;
            w2b = arena + 2048;     b2 = c0m2b;
            w4b = arena + 4096;     b4 = c0m4b;
        } else {
            int m = l - 1;
            w1b = arena + 10240 + m * 4096;  b1 = cm1b + m * 64;
            w2b = arena + 18432 + m * 4096;  b2 = cm2b + m * 64;
            w4b = arena + 26624 + m * 8192;  b4 = cm4b + m * 64;
        }
        if (Cin == 32)
            conv12_s<32><<<512, 512, 0, stream>>>(U[l], aff_s, aff_h, w1b, b1, w2b, b2, O1[l], S2);
        else
            conv12_s<64><<<512, 512, 0, stream>>>(U[l], aff_s, aff_h, w1b, b1, w2b, b2, O1[l], S2);
        bmm_mfma256<<<256, 512, 0, stream>>>(O1[l], S2, S3);
        int nblk;
        if (Cin == 32) {
            conv4_t<3><<<2048, 256, 0, stream>>>(S3, U[l], aff_s, aff_h, w4b, b4, R[l], psum, psq, ptr);
            nblk = 2048;
        } else {
            conv4_s<<<512, 512, 0, stream>>>(S3, U[l], aff_s, aff_h, w4b, b4, R[l], psum, psq, ptr);
            nblk = 512;
        }
        bn_finalize<<<64, 256, 0, stream>>>(psum, psq, ptr, bng + l * 64, bnb + l * 64,
                                            scl, shf, tt + (l + 1) * 128, nblk);
        aff_s = scl; aff_h = shf;
    }
    extractor_par<<<4, 256, 0, stream>>>(tt, np1w, np1b, np2w, np3w,
                                         fe1w, fe1b, fe2w, fe3w, oaccp);
    head_par<<<1, 256, 0, stream>>>(oaccp, acw, acb, flw, flb, out);
}

// Round 12
// 421.461 us; speedup vs baseline: 1.2603x; 1.1602x over previous
//
#include <hip/hip_runtime.h>
#include <hip/hip_bf16.h>

// Problem dims (fixed)
#define Nn   512
#define NN   262144        // N*N positions
#define EDG  16384

typedef unsigned short u16;
typedef unsigned int u32;
typedef short v8s __attribute__((ext_vector_type(8)));   // 8 bf16 lanes (4 VGPR)
typedef float v4f __attribute__((ext_vector_type(4)));
typedef u16 u16x8 __attribute__((ext_vector_type(8)));

__device__ __forceinline__ float b2f(u16 u) {
    union { unsigned int i; float f; } v; v.i = ((unsigned int)u) << 16; return v.f;
}
__device__ __forceinline__ u16 f2b(float f) {
    union { float f; unsigned int i; } v; v.f = f;
    unsigned int r = (v.i + 0x7FFFu + ((v.i >> 16) & 1u)) >> 16;
    return (u16)r;
}
// affine on a packed pair of bf16 (2 positions of one channel)
__device__ __forceinline__ u32 aff2(u32 x, float s, float h) {
    float lo = b2f((u16)(x & 0xFFFFu)) * s + h;
    float hi = b2f((u16)(x >> 16)) * s + h;
    return (u32)f2b(lo) | ((u32)f2b(hi) << 16);
}

// ---------------------------------------------------------------------------
__global__ void sentinel_kernel(float* __restrict__ out, float val) {
    if (threadIdx.x < 10) out[threadIdx.x] = val;
}

// ---------------------------------------------------------------------------
// K0: convert the 6 conv weight tensors (fp32) into one bf16 arena.
__global__ void cvt_weights(const float* __restrict__ s0, const float* __restrict__ s1,
                            const float* __restrict__ s2, const float* __restrict__ s3,
                            const float* __restrict__ s4, const float* __restrict__ s5,
                            u16* __restrict__ dst) {
    int t = blockIdx.x * 256 + threadIdx.x;
    if (t >= 43008) return;
    float v;
    if      (t < 2048)  v = s0[t];
    else if (t < 4096)  v = s1[t - 2048];
    else if (t < 10240) v = s2[t - 4096];
    else if (t < 18432) v = s3[t - 10240];
    else if (t < 26624) v = s4[t - 18432];
    else                v = s5[t - 26624];
    dst[t] = f2b(v);
}

// ---------------------------------------------------------------------------
// K1: scatter edges into A (fp32, pos-major [p][32]); x is fp32 [512][16]
__global__ void scatter_edges(const float* __restrict__ x, const int* __restrict__ ei,
                              float* __restrict__ A) {
    int t = blockIdx.x * 256 + threadIdx.x;
    if (t >= EDG * 32) return;
    int e = t >> 5, c = t & 31;
    int s = ei[e], d = ei[EDG + e];
    float v = (c < 16) ? x[s * 16 + c] : x[d * 16 + (c - 16)];
    atomicAdd(A + ((size_t)s * Nn + d) * 32 + c, v);
}

// ---------------------------------------------------------------------------
// K2: A fp32 pos-major [p][32] -> u0 CHANNEL-MAJOR bf16 [32][NN]; totals into tt0[64..]
__global__ __launch_bounds__(256) void finalize_u0(const float* __restrict__ A,
                                                   u16* __restrict__ u0,
                                                   float* __restrict__ total) {
    __shared__ u16 L[32 * 258];
    __shared__ float red[4][32];
    int t = threadIdx.x;
    int p0 = blockIdx.x * 256;
    const float* Ar = A + (size_t)(p0 + t) * 32;
    float v[32];
#pragma unroll
    for (int c = 0; c < 32; ++c) v[c] = Ar[c];
#pragma unroll
    for (int c = 0; c < 32; ++c) L[c * 258 + t] = f2b(v[c]);
    int wv = t >> 6;
#pragma unroll
    for (int c = 0; c < 32; ++c) {
        float r = v[c];
        for (int off = 32; off > 0; off >>= 1) r += __shfl_down(r, off);
        if ((t & 63) == 0) red[wv][c] = r;
    }
    __syncthreads();
    if (t < 32) atomicAdd(total + t, red[0][t] + red[1][t] + red[2][t] + red[3][t]);
    int off = (t & 31) * 8, rb = t >> 5;
#pragma unroll
    for (int pass = 0; pass < 4; ++pass) {
        int c = pass * 8 + rb;
        u16x8 w = *(const u16x8*)(L + c * 258 + off);
        *(u16x8*)(u0 + (size_t)c * NN + p0 + off) = w;
    }
}

// ---------------------------------------------------------------------------
// K3: trace of channel-major activation; grid = C blocks.
__global__ void trace_raw_cm(const u16* __restrict__ ucm, float* __restrict__ trraw) {
    int c = blockIdx.x, t = threadIdx.x;
    const u16* base = ucm + (size_t)c * NN;
    float s = b2f(base[(size_t)(2 * t) * 513]) + b2f(base[(size_t)(2 * t + 1) * 513]);
    for (int off = 32; off > 0; off >>= 1) s += __shfl_down(s, off);
    __shared__ float r[4];
    if ((t & 63) == 0) r[t >> 6] = s;
    __syncthreads();
    if (t == 0) trraw[c] = r[0] + r[1] + r[2] + r[3];
}

// ---------------------------------------------------------------------------
// K5 v2.1: streaming conv1+conv2 (structure verified r4; PLAIN scalar stores
// — this round is the clean A/B on store flavor, conv4 reverted to conv4_t).
template<int CIN>
__global__ __launch_bounds__(512, 4) void conv12_s(
    const u16* __restrict__ src,
    const float* __restrict__ sc, const float* __restrict__ sh,
    const u16* __restrict__ w1, const float* __restrict__ b1,
    const u16* __restrict__ w2, const float* __restrict__ b2,
    u16* __restrict__ dst1, u16* __restrict__ dst2)
{
    constexpr int G    = CIN / 8;            // 16B granules per position row
    constexpr int LOGG = (CIN == 64) ? 3 : 2;
    constexpr int ROWB = CIN * 2;            // bytes per position row
    constexpr int KC   = CIN / 32;
    constexpr int PASSES = CIN / 32;         // stage passes (512 u32-units each)

    __shared__ char LB[2][128 * ROWB];

    const int t = threadIdx.x;
    const int lane = t & 63, w = t >> 6;
    const int l15 = lane & 15, quad = lane >> 4;
    const int wr = w >> 1;                   // 4 M-groups of 32 rows
    const int wn = w & 1;                    // 2 N-groups of 64 positions
    const size_t Pblk = (size_t)blockIdx.x * 512;

    // ---- stage-role mapping (flat threads)
    const int cpair = (CIN == 64) ? (t >> 4) : (t >> 5);   // channel pair index
    const int pg    = (CIN == 64) ? (t & 15) : (t & 31);   // 4-position group
    const int g0    = cpair >> 2;
    const int word  = cpair & 3;
    const u16* srcA = src + (size_t)(2 * cpair) * NN;
    float s0 = 1.f, h0 = 0.f, s1 = 1.f, h1 = 0.f;
    const bool aff = (sc != nullptr);
    if (aff) { s0 = sc[2 * cpair]; h0 = sh[2 * cpair]; s1 = sc[2 * cpair + 1]; h1 = sh[2 * cpair + 1]; }

    // ---- weights in registers: stacked rows [w1; w2], this wave owns 32 rows
    v8s af[2][KC];
#pragma unroll
    for (int mt = 0; mt < 2; ++mt) {
        const int row = wr * 32 + mt * 16 + l15;
        const u16* Wm = (row < 64) ? (w1 + row * CIN) : (w2 + (row - 64) * CIN);
#pragma unroll
        for (int kc = 0; kc < KC; ++kc)
            af[mt][kc] = *(const v8s*)(Wm + kc * 32 + quad * 8);
    }
    float bias[2][4];
#pragma unroll
    for (int mt = 0; mt < 2; ++mt)
#pragma unroll
        for (int r = 0; r < 4; ++r) {
            const int row = wr * 32 + mt * 16 + quad * 4 + r;
            bias[mt][r] = (row < 64) ? b1[row] : b2[row - 64];
        }

    v4f acc[2][4];
#pragma unroll
    for (int mt = 0; mt < 2; ++mt)
#pragma unroll
        for (int nt = 0; nt < 4; ++nt) acc[mt][nt] = (v4f){0.f, 0.f, 0.f, 0.f};

    uint2 ea[PASSES], eb[PASSES];

#define C12_LOAD(T)                                                           \
    _Pragma("unroll")                                                         \
    for (int pp = 0; pp < PASSES; ++pp) {                                     \
        const int p0_ = (pg + ((CIN == 64) ? 16 : 0) * pp) * 4;               \
        const u16* sp_ = srcA + Pblk + (size_t)(T) * 128 + p0_;               \
        ea[pp] = *(const uint2*)sp_;                                          \
        eb[pp] = *(const uint2*)(sp_ + NN);                                   \
    }

#define C12_WRITE(BUF)                                                        \
    {                                                                         \
        char* Lb_ = LB[BUF];                                                  \
        _Pragma("unroll")                                                     \
        for (int pp = 0; pp < PASSES; ++pp) {                                 \
            const int p0_ = (pg + ((CIN == 64) ? 16 : 0) * pp) * 4;           \
            u32 A0 = ea[pp].x, A1 = ea[pp].y, B0 = eb[pp].x, B1 = eb[pp].y;   \
            if (aff) {                                                        \
                A0 = aff2(A0, s0, h0); A1 = aff2(A1, s0, h0);                 \
                B0 = aff2(B0, s1, h1); B1 = aff2(B1, s1, h1);                 \
            }                                                                 \
            u32 pk0 = (A0 & 0xFFFFu) | (B0 << 16);                            \
            u32 pk1 = (A0 >> 16) | (B0 & 0xFFFF0000u);                        \
            u32 pk2 = (A1 & 0xFFFFu) | (B1 << 16);                            \
            u32 pk3 = (A1 >> 16) | (B1 & 0xFFFF0000u);                        \
            _Pragma("unroll")                                                 \
            for (int w4 = 0; w4 < 4; ++w4) {                                  \
                const int p_ = p0_ + w4;                                      \
                const int g_ = g0 ^ (p_ & (G - 1)) ^ ((p_ >> LOGG) & (G - 1));\
                u32 v_ = (w4 == 0) ? pk0 : (w4 == 1) ? pk1 : (w4 == 2) ? pk2 : pk3; \
                *(u32*)(Lb_ + p_ * ROWB + g_ * 16 + word * 4) = v_;           \
            }                                                                 \
        }                                                                     \
    }

#define C12_COMPUTE(BUF)                                                      \
    _Pragma("unroll")                                                         \
    for (int kc = 0; kc < KC; ++kc) {                                         \
        v8s bf_[4];                                                           \
        const char* Lb_ = LB[BUF];                                            \
        _Pragma("unroll")                                                     \
        for (int nt = 0; nt < 4; ++nt) {                                      \
            const int p_ = wn * 64 + nt * 16 + l15;                           \
            const int lg_ = kc * 4 + quad;                                    \
            const int g_ = lg_ ^ (p_ & (G - 1)) ^ ((p_ >> LOGG) & (G - 1));   \
            bf_[nt] = *(const v8s*)(Lb_ + p_ * ROWB + g_ * 16);               \
        }                                                                     \
        _Pragma("unroll")                                                     \
        for (int mt = 0; mt < 2; ++mt)                                        \
            _Pragma("unroll")                                                 \
            for (int nt = 0; nt < 4; ++nt)                                    \
                acc[mt][nt] = __builtin_amdgcn_mfma_f32_16x16x32_bf16(        \
                    af[mt][kc], bf_[nt], acc[mt][nt], 0, 0, 0);               \
    }

    // ---- prologue
    C12_LOAD(0)
    C12_WRITE(0)
    __syncthreads();

#pragma unroll
    for (int T = 0; T < 4; ++T) {
        const int cur = T & 1;
        if (T < 3) C12_LOAD(T + 1)
        C12_COMPUTE(cur)
        // epilogue: direct channel-major stores (plain, L2 write-combined)
#pragma unroll
        for (int mt = 0; mt < 2; ++mt)
#pragma unroll
            for (int r = 0; r < 4; ++r) {
                const int row = wr * 32 + mt * 16 + quad * 4 + r;
                u16* dp = ((row < 64) ? (dst1 + (size_t)row * NN)
                                      : (dst2 + (size_t)(row - 64) * NN))
                          + Pblk + (size_t)T * 128 + wn * 64 + l15;
#pragma unroll
                for (int nt = 0; nt < 4; ++nt) {
                    dp[nt * 16] = f2b(acc[mt][nt][r] + bias[mt][r]);
                }
            }
        // acc reset for next tile
#pragma unroll
        for (int mt = 0; mt < 2; ++mt)
#pragma unroll
            for (int nt = 0; nt < 4; ++nt) acc[mt][nt] = (v4f){0.f,0.f,0.f,0.f};
        if (T < 3) {
            C12_WRITE(cur ^ 1)
            __syncthreads();
        }
    }
#undef C12_LOAD
#undef C12_WRITE
#undef C12_COMPUTE
}

// ---------------------------------------------------------------------------
// K6: m4 conv (proven, restored for ALL layers — conv4_s experiments r5-r9
// all regressed with 3-4x write amp; conv4_t's LDS-routed full-line u16x8
// stores are clean).
template<int NCH>
__global__ __launch_bounds__(256) void conv4_t(
    const u16* __restrict__ mult, const u16* __restrict__ u,
    const float* __restrict__ sc, const float* __restrict__ sh,
    const u16* __restrict__ w, const float* __restrict__ bias,
    u16* __restrict__ dst,
    float* __restrict__ psum, float* __restrict__ psq, float* __restrict__ ptr)
{
    __shared__ u16 LS[8320];
    __shared__ float R1[64][4], R2[64][4];
    const int K = NCH * 32;
    const int t = threadIdx.x;
    const int P0 = blockIdx.x * 128;
    const int lane = t & 63, wave = t >> 6;
    const int l15 = lane & 15, quad = lane >> 4;
    const int pw = wave * 32;
    const int sr = t >> 4;
    const int so = (t & 15) * 8;

    u16x8 pf[NCH][2];
#pragma unroll
    for (int kc = 0; kc < NCH; ++kc)
#pragma unroll
        for (int ps = 0; ps < 2; ++ps) {
            int cg = kc * 32 + ps * 16 + sr;
            const u16* gp = (cg < 64) ? (mult + (size_t)cg * NN + P0 + so)
                                      : (u + (size_t)(cg - 64) * NN + P0 + so);
            pf[kc][ps] = *(const u16x8*)gp;
        }

    v4f acc[4][2];
#pragma unroll
    for (int mt = 0; mt < 4; ++mt)
#pragma unroll
        for (int nt = 0; nt < 2; ++nt) acc[mt][nt] = (v4f){0.f, 0.f, 0.f, 0.f};

#pragma unroll
    for (int ps = 0; ps < 2; ++ps)
        *(u16x8*)(LS + (ps * 16 + sr) * 130 + so) = pf[0][ps];
    __syncthreads();
#pragma unroll
    for (int kc = 0; kc < NCH; ++kc) {
        if (kc + 1 < NCH) {
            u16* Ln = LS + ((kc + 1) & 1) * 4160;
#pragma unroll
            for (int ps = 0; ps < 2; ++ps) {
                int c = ps * 16 + sr;
                int cg = (kc + 1) * 32 + c;
                u16x8 v = pf[kc + 1][ps];
                if (cg >= 64 && sc) {
                    float s = sc[cg - 64], f = sh[cg - 64];
#pragma unroll
                    for (int j = 0; j < 8; ++j) v[j] = f2b(b2f(v[j]) * s + f);
                }
                *(u16x8*)(Ln + c * 130 + so) = v;
            }
        }
        v8s af[4];
#pragma unroll
        for (int mt = 0; mt < 4; ++mt)
            af[mt] = *(const v8s*)(w + (mt * 16 + l15) * K + kc * 32 + quad * 8);
        const u16* Lb = LS + (kc & 1) * 4160;
#pragma unroll
        for (int nt = 0; nt < 2; ++nt) {
            const int p = pw + nt * 16 + l15;
            v8s b;
#pragma unroll
            for (int j = 0; j < 8; ++j) b[j] = (short)Lb[(quad * 8 + j) * 130 + p];
#pragma unroll
            for (int mt = 0; mt < 4; ++mt)
                acc[mt][nt] = __builtin_amdgcn_mfma_f32_16x16x32_bf16(af[mt], b, acc[mt][nt], 0, 0, 0);
        }
        if (kc + 1 < NCH) __syncthreads();
    }
    __syncthreads();
#pragma unroll
    for (int mt = 0; mt < 4; ++mt)
#pragma unroll
        for (int r = 0; r < 4; ++r) {
            const int h = mt * 16 + quad * 4 + r;
            const float bv = bias[h];
#pragma unroll
            for (int nt = 0; nt < 2; ++nt)
                LS[h * 130 + pw + nt * 16 + l15] = f2b(acc[mt][nt][r] + bv);
        }
    __syncthreads();
    {
        int c = t >> 2, q = t & 3;
        const u16* row = LS + c * 130 + q * 32;
        float s = 0.f, s2 = 0.f;
#pragma unroll
        for (int i = 0; i < 32; ++i) { float v = b2f(row[i]); s += v; s2 += v * v; }
        R1[c][q] = s; R2[c][q] = s2;
    }
    __syncthreads();
    {
        int i = P0 >> 9, j0 = P0 & 511;
        int blk = blockIdx.x;
        if (t < 64) {
            psum[t * 2048 + blk] = R1[t][0] + R1[t][1] + R1[t][2] + R1[t][3];
            psq[t * 2048 + blk]  = R2[t][0] + R2[t][1] + R2[t][2] + R2[t][3];
            if (j0 <= i && i < j0 + 128) ptr[t * 512 + i] = b2f(LS[t * 130 + (i - j0)]);
        }
    }
#pragma unroll
    for (int ps = 0; ps < 4; ++ps) {
        int h = ps * 16 + sr;
        u16x8 v = *(const u16x8*)(LS + h * 130 + so);
        __builtin_nontemporal_store(v, (u16x8*)(dst + (size_t)h * NN + P0 + so));
    }
}

// ---------------------------------------------------------------------------
// K7 v5: batched per-channel GEMM, 256x256 tile, 8 waves (verified r1).
__global__ __launch_bounds__(512, 2) void bmm_mfma256(const u16* __restrict__ Aall,
                                                      const u16* __restrict__ Ball,
                                                      u16* __restrict__ Call) {
    __shared__ u16 LA[2][16384];   // [buf][256 rows][64 k]  (granule-swizzled)
    __shared__ u16 LB[2][16384];   // [buf][256 cols j][64 k] (transposed, swizzled)

    const int bid = blockIdx.x;
    const int h  = ((bid >> 5) << 3) | (bid & 7);   // channel; XCD = h&7
    const int qq = (bid >> 3) & 3;
    const int ty = qq >> 1, tx = qq & 1;
    const int t = threadIdx.x;
    const int l = t & 63, w = t >> 6;
    const int l15 = l & 15, quad = l >> 4;
    const int wr = w >> 2, wc = w & 3;              // 2x4 wave grid

    const u16* Ap = Aall + (size_t)h * NN + (size_t)ty * 256 * 512;
    const u16* Bp = Ball + (size_t)h * NN + tx * 256;
    u16* Cp = Call + (size_t)h * NN;

    const int a_m = l >> 3;
    const int a_kg = (l & 7) ^ a_m;
    const u16* ApL = Ap + (size_t)a_m * 512 + a_kg * 8;   // + cc*4096 + k0

    v4f acc[8][4];
#pragma unroll
    for (int mt = 0; mt < 8; ++mt)
#pragma unroll
        for (int nt = 0; nt < 4; ++nt) acc[mt][nt] = (v4f){0.f, 0.f, 0.f, 0.f};

    uint2 eB[4], oB[4];

#define BMM_BLOAD(K0)                                                         \
    _Pragma("unroll")                                                         \
    for (int L = 0; L < 4; ++L) {                                             \
        const int p = w + 8 * L;                                              \
        const u16* s_ = Bp + (size_t)((K0) + 2 * p) * 512 + l * 4;            \
        eB[L] = *(const uint2*)s_;                                            \
        oB[L] = *(const uint2*)(s_ + 512);                                    \
    }

#define BMM_ALOAD(BUF, K0)                                                    \
    _Pragma("unroll")                                                         \
    for (int c = 0; c < 4; ++c) {                                             \
        const int cc = w * 4 + c;                                             \
        __builtin_amdgcn_global_load_lds(                                     \
            (const void*)(ApL + (size_t)cc * 4096 + (K0)),                    \
            (void*)&LA[BUF][cc * 512], 16, 0, 0);                             \
    }

#define BMM_BWRITE(BUF)                                                       \
    {                                                                         \
        char* base_ = (char*)&LB[BUF][0];                                     \
        _Pragma("unroll")                                                     \
        for (int L = 0; L < 4; ++L) {                                         \
            const int p = w + 8 * L;                                          \
            const int gk = p >> 2, wd = p & 3;                                \
            u32 e0 = eB[L].x, e1 = eB[L].y, o0 = oB[L].x, o1 = oB[L].y;       \
            u32 pk0 = (e0 & 0xFFFFu) | (o0 << 16);                            \
            u32 pk1 = (e0 >> 16) | (o0 & 0xFFFF0000u);                        \
            u32 pk2 = (e1 & 0xFFFFu) | (o1 << 16);                            \
            u32 pk3 = (e1 >> 16) | (o1 & 0xFFFF0000u);                        \
            _Pragma("unroll")                                                 \
            for (int q = 0; q < 4; ++q) {                                     \
                const int j = l * 4 + q;                                      \
                const int g = gk ^ (j & 7) ^ ((j >> 3) & 7);                  \
                u32 v_ = (q == 0) ? pk0 : (q == 1) ? pk1 : (q == 2) ? pk2 : pk3; \
                *(u32*)(base_ + j * 128 + (g << 4) + wd * 4) = v_;            \
            }                                                                 \
        }                                                                     \
    }

#define BMM_COMPUTE(BUF)                                                      \
    _Pragma("unroll")                                                         \
    for (int kk = 0; kk < 2; ++kk) {                                          \
        v8s af_[8], bf_[4];                                                   \
        const char* baseA_ = (const char*)&LA[BUF][0];                        \
        const char* baseB_ = (const char*)&LB[BUF][0];                        \
        _Pragma("unroll")                                                     \
        for (int mt = 0; mt < 8; ++mt) {                                      \
            const int m = wr * 128 + mt * 16 + l15;                           \
            const int g = (kk * 4 + quad) ^ (m & 7);                          \
            af_[mt] = *(const v8s*)(baseA_ + m * 128 + (g << 4));             \
        }                                                                     \
        _Pragma("unroll")                                                     \
        for (int nt = 0; nt < 4; ++nt) {                                      \
            const int j = wc * 64 + nt * 16 + l15;                            \
            const int g = (kk * 4 + quad) ^ (j & 7) ^ ((j >> 3) & 7);         \
            bf_[nt] = *(const v8s*)(baseB_ + j * 128 + (g << 4));             \
        }                                                                     \
        _Pragma("unroll")                                                     \
        for (int mt = 0; mt < 8; ++mt)                                        \
            _Pragma("unroll")                                                 \
            for (int nt = 0; nt < 4; ++nt)                                    \
                acc[mt][nt] = __builtin_amdgcn_mfma_f32_16x16x32_bf16(        \
                    af_[mt], bf_[nt], acc[mt][nt], 0, 0, 0);                  \
    }

    BMM_BLOAD(0)
    BMM_ALOAD(0, 0)
    BMM_BWRITE(0)
    __syncthreads();

#pragma unroll 2
    for (int ts = 0; ts < 8; ++ts) {
        const int cur = ts & 1;
        if (ts < 7) {
            BMM_BLOAD((ts + 1) * 64)
            BMM_ALOAD(cur ^ 1, (ts + 1) * 64)
        }
        BMM_COMPUTE(cur)
        if (ts < 7) {
            BMM_BWRITE(cur ^ 1)
            __syncthreads();
        }
    }

#pragma unroll
    for (int mt = 0; mt < 8; ++mt)
#pragma unroll
        for (int r = 0; r < 4; ++r) {
            const int i = ty * 256 + wr * 128 + mt * 16 + quad * 4 + r;
#pragma unroll
            for (int nt = 0; nt < 4; ++nt) {
                const int j = tx * 256 + wc * 64 + nt * 16 + l15;
                Cp[(size_t)i * 512 + j] = f2b(acc[mt][nt][r]);
            }
        }
#undef BMM_BLOAD
#undef BMM_ALOAD
#undef BMM_BWRITE
#undef BMM_COMPUTE
}

// ---------------------------------------------------------------------------
// K11: reduce per-block partials; BN scale/shift; normalized totals & trace.
__global__ __launch_bounds__(256) void bn_finalize(
    const float* __restrict__ psum, const float* __restrict__ psq,
    const float* __restrict__ ptr,
    const float* __restrict__ g, const float* __restrict__ b,
    float* __restrict__ scale, float* __restrict__ shift,
    float* __restrict__ ttl) {
    int c = blockIdx.x, t = threadIdx.x;
    float s = 0.f, q = 0.f, tr = 0.f;
    for (int k = t; k < 2048; k += 256) { s += psum[c * 2048 + k]; q += psq[c * 2048 + k]; }
    for (int k = t; k < 512; k += 256) tr += ptr[c * 512 + k];
    for (int off = 32; off > 0; off >>= 1) {
        s += __shfl_down(s, off); q += __shfl_down(q, off); tr += __shfl_down(tr, off);
    }
    __shared__ float r1[4], r2[4], r3[4];
    if ((t & 63) == 0) { r1[t >> 6] = s; r2[t >> 6] = q; r3[t >> 6] = tr; }
    __syncthreads();
    if (t == 0) {
        s = r1[0] + r1[1] + r1[2] + r1[3];
        q = r2[0] + r2[1] + r2[2] + r2[3];
        tr = r3[0] + r3[1] + r3[2] + r3[3];
        float mean = s * (1.f / 262144.f);
        float var = q * (1.f / 262144.f) - mean * mean;
        float sc = g[c] * rsqrtf(fmaxf(var, 0.f) + 1e-5f);
        float sh = b[c] - mean * sc;
        scale[c] = sc;
        shift[c] = sh;
        ttl[64 + c] = sc * s + 262144.f * sh;   // total
        ttl[c]      = sc * tr + 512.f * sh;     // trace
    }
}

// ---------------------------------------------------------------------------
// K12a: one extractor per block (4 blocks, 256 thr). thread=(h,q): q = c-quarter.
__global__ __launch_bounds__(256) void extractor_par(
    const float* __restrict__ tt,
    const float* __restrict__ np1w, const float* __restrict__ np1b,
    const float* __restrict__ np2w, const float* __restrict__ np3w,
    const float* __restrict__ fe1w, const float* __restrict__ fe1b,
    const float* __restrict__ fe2w, const float* __restrict__ fe3w,
    float* __restrict__ oacc_part) {
    __shared__ float red[64][4];
    __shared__ float xo[64];
    const int li = blockIdx.x;
    const int t = threadIdx.x;
    const int h = t >> 2, q = t & 3;
    const int C = (li == 0) ? 32 : 64;
    const float* w1 = (li == 0) ? np1w : fe1w + (li - 1) * 4096;
    const float* b1 = (li == 0) ? np1b : fe1b + (li - 1) * 64;
    const float* w2 = (li == 0) ? np2w : fe2w + (li - 1) * 4096;
    const float* w3 = (li == 0) ? np3w : fe3w + (li - 1) * 4096;
    const float* tr = tt + li * 128;
    const float* to = tr + 64;
    const int cpq = C >> 2;
    float p = 0.f;
    for (int i = 0; i < cpq; ++i) {
        int c = q * cpq + i;
        p += (tr[c] * (1.f / 512.f)) * w1[h * C + c]
           + ((to[c] - tr[c]) * (1.f / (512.f * 511.f))) * w2[h * C + c];
    }
    red[h][q] = p;
    __syncthreads();
    if (q == 0) xo[h] = b1[h] + red[h][0] + red[h][1] + red[h][2] + red[h][3];
    __syncthreads();
    float o = xo[h];
    float p3 = 0.f;
    for (int i = 0; i < 16; ++i) {
        int f = q * 16 + i;
        p3 += fmaxf(xo[f], 0.f) * w3[h * 64 + f];
    }
    __syncthreads();
    red[h][q] = p3;
    __syncthreads();
    if (q == 0) oacc_part[li * 64 + h] = o + red[h][0] + red[h][1] + red[h][2] + red[h][3];
}

// ---------------------------------------------------------------------------
// K12b: head, 256 threads, 4-way split per output.
__global__ __launch_bounds__(256) void head_par(
    const float* __restrict__ oacc_part,
    const float* __restrict__ acw, const float* __restrict__ acb,
    const float* __restrict__ flw, const float* __restrict__ flb,
    float* __restrict__ out) {
    __shared__ float x[64], x2[64], red[64][4], l[10];
    const int t = threadIdx.x;
    const int h = t >> 2, q = t & 3;
    if (q == 0) {
        float oa = oacc_part[h] + oacc_part[64 + h] + oacc_part[128 + h] + oacc_part[192 + h];
        x[h] = fmaxf(oa, 0.f) * (1.f / 3.f);
    }
    __syncthreads();
    float p = 0.f;
    for (int i = 0; i < 16; ++i) { int f = q * 16 + i; p += x[f] * acw[h * 64 + f]; }
    red[h][q] = p;
    __syncthreads();
    if (q == 0) {
        float y = acb[h] + red[h][0] + red[h][1] + red[h][2] + red[h][3];
        x2[h] = x[h] + fmaxf(y, 0.f);
    }
    __syncthreads();
    if (t < 40) {
        int hh = t >> 2, qq = t & 3;
        float p2 = 0.f;
        for (int i = 0; i < 16; ++i) { int f = qq * 16 + i; p2 += x2[f] * flw[hh * 64 + f]; }
        red[hh][qq] = p2;
    }
    __syncthreads();
    if (t < 10) l[t] = flb[t] + red[t][0] + red[t][1] + red[t][2] + red[t][3];
    __syncthreads();
    if (t == 0) {
        float m = l[0];
        for (int i = 1; i < 10; ++i) m = fmaxf(m, l[i]);
        float se = 0.f;
        for (int i = 0; i < 10; ++i) se += expf(l[i] - m);
        float ls = m + logf(se);
        for (int i = 0; i < 10; ++i) out[i] = l[i] - ls;
    }
}

// ---------------------------------------------------------------------------
extern "C" void kernel_launch(void* const* d_in, const int* in_sizes, int n_in,
                              void* d_out, int out_size, void* d_ws, size_t ws_size,
                              hipStream_t stream) {
    float* out = (float*)d_out;

    static const int exp_sizes[28] = {
        8192, 32768,
        2048, 64, 2048, 4096,
        2048, 64, 2048, 64, 6144, 64,
        8192, 128, 8192, 128, 16384, 128,
        192, 192,
        12288, 192, 12288, 12288,
        4096, 64, 640, 10
    };
    bool ok = (n_in == 28);
    if (ok) for (int i = 0; i < 28; ++i) if (in_sizes[i] != exp_sizes[i]) ok = false;
    if (!ok) { sentinel_kernel<<<1, 64, 0, stream>>>(out, -5.0f); return; }

    const size_t RSZ = (size_t)NN * 64 * 2;            // 33.55 MB per region
    const size_t BIG_OFF = 8192 + 90112;               // control (8KB) + bf16 weight arena
    if (ws_size < BIG_OFF + 4 * RSZ) {
        sentinel_kernel<<<1, 64, 0, stream>>>(out, -7.0f);
        return;
    }

    const float* x     = (const float*)d_in[0];
    const int*   ei    = (const int*)d_in[1];
    const float* np1w  = (const float*)d_in[2];
    const float* np1b  = (const float*)d_in[3];
    const float* np2w  = (const float*)d_in[4];
    const float* np3w  = (const float*)d_in[5];
    const float* c0m1b = (const float*)d_in[7];
    const float* c0m2b = (const float*)d_in[9];
    const float* c0m4b = (const float*)d_in[11];
    const float* cm1b  = (const float*)d_in[13];
    const float* cm2b  = (const float*)d_in[15];
    const float* cm4b  = (const float*)d_in[17];
    const float* bng   = (const float*)d_in[18];
    const float* bnb   = (const float*)d_in[19];
    const float* fe1w  = (const float*)d_in[20];
    const float* fe1b  = (const float*)d_in[21];
    const float* fe2w  = (const float*)d_in[22];
    const float* fe3w  = (const float*)d_in[23];
    const float* acw   = (const float*)d_in[24];
    const float* acb   = (const float*)d_in[25];
    const float* flw   = (const float*)d_in[26];
    const float* flb   = (const float*)d_in[27];

    char* ws = (char*)d_ws;
    float* small = (float*)ws;
    float* tt    = small;          // [4][128]: per-layer trace(64)|total(64)
    float* scl   = small + 512;
    float* shf   = small + 576;
    float* oaccp = small + 640;    // [4][64] extractor partials

    u16* arena = (u16*)(ws + 8192);          // bf16 conv weights, 43008 elements

    char* big = ws + BIG_OFF;
    u16* S0 = (u16*)(big + 0 * RSZ);
    u16* S1 = (u16*)(big + 1 * RSZ);
    u16* S2 = (u16*)(big + 2 * RSZ);
    u16* S3 = (u16*)(big + 3 * RSZ);
    float* Abuf = (float*)S2;                // fp32 staging, dead after finalize_u0

    // BN partial buffers live in S2 (o2 slot) — dead between bmm and next conv12.
    float* psum = (float*)S2;                          // 64*2048
    float* psq  = psum + 64 * 2048;                    // 64*2048
    float* ptr  = psq + 64 * 2048;                     // 64*512

    hipMemsetAsync(small, 0, 4096, stream);
    hipMemsetAsync(Abuf, 0, (size_t)NN * 32 * 4, stream);

    cvt_weights<<<168, 256, 0, stream>>>((const float*)d_in[6], (const float*)d_in[8],
                                         (const float*)d_in[10], (const float*)d_in[12],
                                         (const float*)d_in[14], (const float*)d_in[16], arena);
    scatter_edges<<<2048, 256, 0, stream>>>(x, ei, Abuf);
    finalize_u0<<<1024, 256, 0, stream>>>(Abuf, S0, tt + 64);        // total -> tt[0][64..]
    trace_raw_cm<<<32, 256, 0, stream>>>(S0, tt);                    // trace -> tt[0][0..31]

    u16* U[3]  = { S0, S1, S0 };
    u16* O1[3] = { S1, S0, S1 };
    u16* R[3]  = { S1, S0, S1 };

    const float *aff_s = nullptr, *aff_h = nullptr;

    for (int l = 0; l < 3; ++l) {
        int Cin = (l == 0) ? 32 : 64;
        const u16 *w1b, *w2b, *w4b;
        const float *b1, *b2, *b4;
        if (l == 0) {
            w1b = arena;            b1 = c0m1b;
            w2b = arena + 2048;     b2 = c0m2b;
            w4b = arena + 4096;     b4 = c0m4b;
        } else {
            int m = l - 1;
            w1b = arena + 10240 + m * 4096;  b1 = cm1b + m * 64;
            w2b = arena + 18432 + m * 4096;  b2 = cm2b + m * 64;
            w4b = arena + 26624 + m * 8192;  b4 = cm4b + m * 64;
        }
        if (Cin == 32)
            conv12_s<32><<<512, 512, 0, stream>>>(U[l], aff_s, aff_h, w1b, b1, w2b, b2, O1[l], S2);
        else
            conv12_s<64><<<512, 512, 0, stream>>>(U[l], aff_s, aff_h, w1b, b1, w2b, b2, O1[l], S2);
        bmm_mfma256<<<256, 512, 0, stream>>>(O1[l], S2, S3);
        if (Cin == 32)
            conv4_t<3><<<2048, 256, 0, stream>>>(S3, U[l], aff_s, aff_h, w4b, b4, R[l], psum, psq, ptr);
        else
            conv4_t<4><<<2048, 256, 0, stream>>>(S3, U[l], aff_s, aff_h, w4b, b4, R[l], psum, psq, ptr);
        bn_finalize<<<64, 256, 0, stream>>>(psum, psq, ptr, bng + l * 64, bnb + l * 64,
                                            scl, shf, tt + (l + 1) * 128);
        aff_s = scl; aff_h = shf;
    }
    extractor_par<<<4, 256, 0, stream>>>(tt, np1w, np1b, np2w, np3w,
                                         fe1w, fe1b, fe2w, fe3w, oaccp);
    head_par<<<1, 256, 0, stream>>>(oaccp, acw, acb, flw, flb, out);
}